// Round 1
// baseline (1475.423 us; speedup 1.0000x reference)
//
#include <hip/hip_runtime.h>
#include <hip/hip_bf16.h>

#define BSZ 32
#define CIN 128
#define CD 64
#define HH 64
#define WW 64
#define PLANE (HH * WW)
#define NPIX (BSZ * HH * WW)
#define NB 8
#define BN_EPS 1e-5f

// ---------------------------------------------------------------------------
// K1: 1x1 conv 128->64 (dim_reduce). Block per (b,h) row: stage x[128][64] in
// LDS, each thread computes 16 output channels for one w. Coalesced in+out.
// ---------------------------------------------------------------------------
__global__ __launch_bounds__(256) void k_reduce(
    const float* __restrict__ x, const float* __restrict__ wgt,
    const float* __restrict__ bias, float* __restrict__ out)
{
    __shared__ float xs[CIN][WW];  // 32 KB
    const int bh = blockIdx.x;
    const int b = bh >> 6, h = bh & 63;
    const float* xin = x + (size_t)b * CIN * PLANE + h * WW;
    for (int i = threadIdx.x; i < CIN * WW; i += 256) {
        int c = i >> 6, w = i & 63;
        xs[c][w] = xin[(size_t)c * PLANE + w];
    }
    __syncthreads();
    const int w = threadIdx.x & 63;
    const int o0 = (threadIdx.x >> 6) * 16;  // wave-uniform
    float acc[16];
#pragma unroll
    for (int k = 0; k < 16; ++k) acc[k] = bias[o0 + k];
    for (int c = 0; c < CIN; c += 4) {
        float x0 = xs[c][w], x1 = xs[c + 1][w], x2 = xs[c + 2][w], x3 = xs[c + 3][w];
#pragma unroll
        for (int k = 0; k < 16; ++k) {
            const float4 wv = *(const float4*)(wgt + (o0 + k) * CIN + c);
            acc[k] = fmaf(x0, wv.x, fmaf(x1, wv.y, fmaf(x2, wv.z, fmaf(x3, wv.w, acc[k]))));
        }
    }
    float* op = out + (size_t)b * CD * PLANE + h * WW + w;
#pragma unroll
    for (int k = 0; k < 16; ++k) op[(size_t)(o0 + k) * PLANE] = acc[k];
}

// ---------------------------------------------------------------------------
// K2: 7x7 depthwise conv + BN. Block per (b,h): each thread computes 16
// channels for one w (coalesced NCHW reads), LDS transpose, write NHWC
// coalesced (so the KAN token kernel reads contiguous 64-ch vectors).
// ---------------------------------------------------------------------------
__global__ __launch_bounds__(256) void k_dwbn(
    const float* __restrict__ in, const float* __restrict__ wgt,
    const float* __restrict__ bias, const float* __restrict__ bg,
    const float* __restrict__ bb, const float* __restrict__ bm,
    const float* __restrict__ bv, float* __restrict__ out_nhwc)
{
    __shared__ float tile[CD][WW + 1];  // +1 pad: conflict-free transpose
    const int bh = blockIdx.x;
    const int b = bh >> 6, h = bh & 63;
    const int w = threadIdx.x & 63;
    const int c0 = (threadIdx.x >> 6) * 16;  // wave-uniform
    const float* base = in + (size_t)b * CD * PLANE;
#pragma unroll 1
    for (int k = 0; k < 16; ++k) {
        const int c = c0 + k;
        const float* wp = wgt + c * 49;
        float acc = 0.f;
#pragma unroll
        for (int dy = 0; dy < 7; ++dy) {
            const int hy = h + dy - 3;
            if (hy < 0 || hy >= HH) continue;  // uniform branch
            const float* rp = base + (size_t)c * PLANE + hy * WW;
#pragma unroll
            for (int dx = 0; dx < 7; ++dx) {
                const int wx = w + dx - 3;
                float xv = (wx >= 0 && wx < WW) ? rp[wx] : 0.f;
                acc = fmaf(xv, wp[dy * 7 + dx], acc);
            }
        }
        float inv = rsqrtf(bv[c] + BN_EPS);
        tile[c][w] = bg[c] * (acc + bias[c] - bm[c]) * inv + bb[c];
    }
    __syncthreads();
    const int c2 = threadIdx.x & 63;
    const int wl = (threadIdx.x >> 6) * 16;
    float* orow = out_nhwc + (size_t)bh * WW * CD;
#pragma unroll
    for (int k = 0; k < 16; ++k) {
        int w2 = wl + k;
        orow[w2 * CD + c2] = tile[c2][w2];  // 256B-contig per w2
    }
}

// ---------------------------------------------------------------------------
// K3: fused KAN layer + f2 1x1 conv + elementwise gate, tokenwise, IN-PLACE
// on the NHWC buffer (each block only touches its own 1KB token span).
// 4 tokens per 256-thread block; lane j = output channel.
// ---------------------------------------------------------------------------
__global__ __launch_bounds__(256) void k_kan(
    float* __restrict__ xdio,  // in: xd NHWC, out: y = x1*x2 NHWC
    const float* __restrict__ coef, const float* __restrict__ sb,
    const float* __restrict__ ssp, const float* __restrict__ kb,
    const float* __restrict__ f2w, const float* __restrict__ f2b)
{
    __shared__ float vsh[4][CD];
    __shared__ float ssh[4][CD];
    __shared__ float Bsh[4][NB][CD];  // [t][j] layout: conflict-free writes
    const int tid = threadIdx.x;
    const int lt = tid >> 6;  // local token (wave id)
    const int j = tid & 63;   // output channel
    const size_t base = (size_t)blockIdx.x * 4 * CD;
    const float v = xdio[base + tid];  // fully coalesced
    const float s = v / (1.0f + expf(-v));  // silu

    // degree-3 B-spline basis, uniform knots t[q] = (q-3)*0.4 - 1, q=0..11
    float Bl[11];
#pragma unroll
    for (int q = 0; q < 11; ++q) {
        float t0 = (q - 3) * 0.4f - 1.0f;
        float t1 = (q - 2) * 0.4f - 1.0f;
        Bl[q] = (v >= t0 && v < t1) ? 1.0f : 0.0f;
    }
#pragma unroll
    for (int p = 1; p <= 3; ++p) {
        const float inv = 1.0f / (0.4f * p);
#pragma unroll
        for (int q = 0; q < 11 - p; ++q) {
            float tq = (q - 3) * 0.4f - 1.0f;       // t[q]
            float tqp1 = (q + p - 2) * 0.4f - 1.0f; // t[q+p+1]
            Bl[q] = (v - tq) * inv * Bl[q] + (tqp1 - v) * inv * Bl[q + 1];
        }
    }
    vsh[lt][j] = v;
    ssh[lt][j] = s;
#pragma unroll
    for (int t = 0; t < NB; ++t) Bsh[lt][t][j] = Bl[t];
    __syncthreads();

    float acc1 = kb[j];   // x1 = y_base + y_sp + kan_bias
    float acc2 = f2b[j];  // x2 = f2 conv
    for (int i = 0; i < CD; ++i) {
        float sv = ssh[lt][i];  // LDS broadcast
        float vv = vsh[lt][i];
        acc1 = fmaf(sv, sb[i * CD + j], acc1);   // coalesced across j
        acc2 = fmaf(vv, f2w[j * CD + i], acc2);  // L1-resident 16KB
        const float4* cp = (const float4*)(coef + (size_t)(i * CD + j) * NB);
        float4 c0 = cp[0], c1 = cp[1];  // coalesced 32B/lane
        float sp = c0.x * Bsh[lt][0][i] + c0.y * Bsh[lt][1][i]
                 + c0.z * Bsh[lt][2][i] + c0.w * Bsh[lt][3][i]
                 + c1.x * Bsh[lt][4][i] + c1.y * Bsh[lt][5][i]
                 + c1.z * Bsh[lt][6][i] + c1.w * Bsh[lt][7][i];
        acc1 = fmaf(ssp[i * CD + j], sp, acc1);
    }
    xdio[base + tid] = acc1 * acc2;  // y = x1 * x2, coalesced
}

// ---------------------------------------------------------------------------
// K4: g 1x1 conv + BN. Block per (b,h): stage y row (NHWC) in LDS, compute,
// write NCHW coalesced across w.
// ---------------------------------------------------------------------------
__global__ __launch_bounds__(256) void k_gbn(
    const float* __restrict__ y, const float* __restrict__ wgt,
    const float* __restrict__ bias, const float* __restrict__ bg,
    const float* __restrict__ bb, const float* __restrict__ bm,
    const float* __restrict__ bv, float* __restrict__ z)
{
    __shared__ float ys[WW][CD + 1];  // +1 pad
    const int bh = blockIdx.x;
    const int b = bh >> 6, h = bh & 63;
    const float* yrow = y + (size_t)bh * WW * CD;
    for (int i = threadIdx.x; i < WW * CD; i += 256)
        ys[i >> 6][i & 63] = yrow[i];
    __syncthreads();
    const int w = threadIdx.x & 63;
    const int o0 = (threadIdx.x >> 6) * 16;
    float acc[16];
#pragma unroll
    for (int k = 0; k < 16; ++k) acc[k] = bias[o0 + k];
    for (int i = 0; i < CD; i += 4) {
        float y0 = ys[w][i], y1 = ys[w][i + 1], y2 = ys[w][i + 2], y3 = ys[w][i + 3];
#pragma unroll
        for (int k = 0; k < 16; ++k) {
            const float4 wv = *(const float4*)(wgt + (o0 + k) * CD + i);
            acc[k] = fmaf(y0, wv.x, fmaf(y1, wv.y, fmaf(y2, wv.z, fmaf(y3, wv.w, acc[k]))));
        }
    }
    float* op = z + (size_t)b * CD * PLANE + h * WW + w;
#pragma unroll
    for (int k = 0; k < 16; ++k) {
        int o = o0 + k;
        float inv = rsqrtf(bv[o] + BN_EPS);
        op[(size_t)o * PLANE] = bg[o] * (acc[k] - bm[o]) * inv + bb[o];
    }
}

// ---------------------------------------------------------------------------
// K5: 7x7 depthwise conv + bias + residual add -> d_out (NCHW).
// ---------------------------------------------------------------------------
__global__ __launch_bounds__(256) void k_dw2(
    const float* __restrict__ z, const float* __restrict__ wgt,
    const float* __restrict__ bias, const float* __restrict__ inp,
    float* __restrict__ out)
{
    const int bh = blockIdx.x;
    const int b = bh >> 6, h = bh & 63;
    const int w = threadIdx.x & 63;
    const int c0 = (threadIdx.x >> 6) * 16;
    const float* base = z + (size_t)b * CD * PLANE;
#pragma unroll 1
    for (int k = 0; k < 16; ++k) {
        const int c = c0 + k;
        const float* wp = wgt + c * 49;
        float acc = bias[c];
#pragma unroll
        for (int dy = 0; dy < 7; ++dy) {
            const int hy = h + dy - 3;
            if (hy < 0 || hy >= HH) continue;
            const float* rp = base + (size_t)c * PLANE + hy * WW;
#pragma unroll
            for (int dx = 0; dx < 7; ++dx) {
                const int wx = w + dx - 3;
                float xv = (wx >= 0 && wx < WW) ? rp[wx] : 0.f;
                acc = fmaf(xv, wp[dy * 7 + dx], acc);
            }
        }
        size_t oi = ((size_t)b * CD + c) * PLANE + h * WW + w;
        out[oi] = inp[oi] + acc;
    }
}

// ---------------------------------------------------------------------------
extern "C" void kernel_launch(void* const* d_in, const int* in_sizes, int n_in,
                              void* d_out, int out_size, void* d_ws, size_t ws_size,
                              hipStream_t stream)
{
    (void)in_sizes; (void)n_in; (void)out_size; (void)ws_size;
    const float* x        = (const float*)d_in[0];
    const float* reduce_w = (const float*)d_in[1];
    const float* reduce_b = (const float*)d_in[2];
    const float* dw_w     = (const float*)d_in[3];
    const float* dw_b     = (const float*)d_in[4];
    const float* dw_g     = (const float*)d_in[5];
    const float* dw_beta  = (const float*)d_in[6];
    const float* dw_m     = (const float*)d_in[7];
    const float* dw_v     = (const float*)d_in[8];
    const float* f2_w     = (const float*)d_in[9];
    const float* f2_b     = (const float*)d_in[10];
    const float* coef     = (const float*)d_in[11];
    const float* sbase    = (const float*)d_in[12];
    const float* ssp      = (const float*)d_in[13];
    const float* kbias    = (const float*)d_in[14];
    const float* g_w      = (const float*)d_in[15];
    const float* g_b      = (const float*)d_in[16];
    const float* g_g      = (const float*)d_in[17];
    const float* g_beta   = (const float*)d_in[18];
    const float* g_m      = (const float*)d_in[19];
    const float* g_v      = (const float*)d_in[20];
    const float* dw2_w    = (const float*)d_in[21];
    const float* dw2_b    = (const float*)d_in[22];
    float* out = (float*)d_out;

    const size_t NEL = (size_t)BSZ * CD * PLANE;  // 8388608 floats = 32 MB
    float* inp = (float*)d_ws;    // reduce output, NCHW (residual source)
    float* xd  = inp + NEL;       // dwconv+BN output NHWC; gated y in-place
    float* z   = xd + NEL;        // g-conv+BN output NCHW

    k_reduce<<<BSZ * HH, 256, 0, stream>>>(x, reduce_w, reduce_b, inp);
    k_dwbn<<<BSZ * HH, 256, 0, stream>>>(inp, dw_w, dw_b, dw_g, dw_beta, dw_m, dw_v, xd);
    k_kan<<<NPIX / 4, 256, 0, stream>>>(xd, coef, sbase, ssp, kbias, f2_w, f2_b);
    k_gbn<<<BSZ * HH, 256, 0, stream>>>(xd, g_w, g_b, g_g, g_beta, g_m, g_v, z);
    k_dw2<<<BSZ * HH, 256, 0, stream>>>(z, dw2_w, dw2_b, inp, out);
}

// Round 2
// 511.834 us; speedup vs baseline: 2.8826x; 2.8826x over previous
//
#include <hip/hip_runtime.h>
#include <hip/hip_bf16.h>

#define BSZ 32
#define CIN 128
#define CD 64
#define HH 64
#define WW 64
#define PLANE (HH * WW)
#define NPIX (BSZ * HH * WW)
#define NB 8
#define BN_EPS 1e-5f

typedef __attribute__((ext_vector_type(8))) short short8v;
typedef __attribute__((ext_vector_type(4))) float f32x4;

static __device__ __forceinline__ short f2bf(float f) {
    __hip_bfloat16 h = __float2bfloat16(f);
    return __builtin_bit_cast(short, h);
}

// ---------------------------------------------------------------------------
// K1: 1x1 conv 128->64 (dim_reduce). (unchanged from round 1)
// ---------------------------------------------------------------------------
__global__ __launch_bounds__(256) void k_reduce(
    const float* __restrict__ x, const float* __restrict__ wgt,
    const float* __restrict__ bias, float* __restrict__ out)
{
    __shared__ float xs[CIN][WW];
    const int bh = blockIdx.x;
    const int b = bh >> 6, h = bh & 63;
    const float* xin = x + (size_t)b * CIN * PLANE + h * WW;
    for (int i = threadIdx.x; i < CIN * WW; i += 256) {
        int c = i >> 6, w = i & 63;
        xs[c][w] = xin[(size_t)c * PLANE + w];
    }
    __syncthreads();
    const int w = threadIdx.x & 63;
    const int o0 = (threadIdx.x >> 6) * 16;
    float acc[16];
#pragma unroll
    for (int k = 0; k < 16; ++k) acc[k] = bias[o0 + k];
    for (int c = 0; c < CIN; c += 4) {
        float x0 = xs[c][w], x1 = xs[c + 1][w], x2 = xs[c + 2][w], x3 = xs[c + 3][w];
#pragma unroll
        for (int k = 0; k < 16; ++k) {
            const float4 wv = *(const float4*)(wgt + (o0 + k) * CIN + c);
            acc[k] = fmaf(x0, wv.x, fmaf(x1, wv.y, fmaf(x2, wv.z, fmaf(x3, wv.w, acc[k]))));
        }
    }
    float* op = out + (size_t)b * CD * PLANE + h * WW + w;
#pragma unroll
    for (int k = 0; k < 16; ++k) op[(size_t)(o0 + k) * PLANE] = acc[k];
}

// ---------------------------------------------------------------------------
// K2: 7x7 depthwise conv + BN -> NHWC. (unchanged from round 1)
// ---------------------------------------------------------------------------
__global__ __launch_bounds__(256) void k_dwbn(
    const float* __restrict__ in, const float* __restrict__ wgt,
    const float* __restrict__ bias, const float* __restrict__ bg,
    const float* __restrict__ bb, const float* __restrict__ bm,
    const float* __restrict__ bv, float* __restrict__ out_nhwc)
{
    __shared__ float tile[CD][WW + 1];
    const int bh = blockIdx.x;
    const int b = bh >> 6, h = bh & 63;
    const int w = threadIdx.x & 63;
    const int c0 = (threadIdx.x >> 6) * 16;
    const float* base = in + (size_t)b * CD * PLANE;
#pragma unroll 1
    for (int k = 0; k < 16; ++k) {
        const int c = c0 + k;
        const float* wp = wgt + c * 49;
        float acc = 0.f;
#pragma unroll
        for (int dy = 0; dy < 7; ++dy) {
            const int hy = h + dy - 3;
            if (hy < 0 || hy >= HH) continue;
            const float* rp = base + (size_t)c * PLANE + hy * WW;
#pragma unroll
            for (int dx = 0; dx < 7; ++dx) {
                const int wx = w + dx - 3;
                float xv = (wx >= 0 && wx < WW) ? rp[wx] : 0.f;
                acc = fmaf(xv, wp[dy * 7 + dx], acc);
            }
        }
        float inv = rsqrtf(bv[c] + BN_EPS);
        tile[c][w] = bg[c] * (acc + bias[c] - bm[c]) * inv + bb[c];
    }
    __syncthreads();
    const int c2 = threadIdx.x & 63;
    const int wl = (threadIdx.x >> 6) * 16;
    float* orow = out_nhwc + (size_t)bh * WW * CD;
#pragma unroll
    for (int k = 0; k < 16; ++k) {
        int w2 = wl + k;
        orow[w2 * CD + c2] = tile[c2][w2];
    }
}

// ---------------------------------------------------------------------------
// K0: prepack weights into MFMA B-fragment order (bf16).
// W1 [576][64]: rows 0..511 = coef[i][j][t]*ssp[i][j] at k=i*8+t; rows
// 512..575 = scale_base. W2 [64][64] = f2w^T. Fragment layout: element
// ((s*4+c)*64+l)*8+e  holds  W[k = s*32 + (l>>4)*8 + e][j = c*16 + (l&15)].
// ---------------------------------------------------------------------------
__global__ __launch_bounds__(256) void k_prep(
    const float* __restrict__ coef, const float* __restrict__ ssp,
    const float* __restrict__ sb, const float* __restrict__ f2w,
    short* __restrict__ W1f, short* __restrict__ W2f)
{
    const int idx = blockIdx.x * 256 + threadIdx.x;
    if (idx < 36864) {
        const int e = idx & 7, l = (idx >> 3) & 63, c = (idx >> 9) & 3, s = idx >> 11;
        const int k = s * 32 + ((l >> 4) << 3) + e;
        const int j = (c << 4) + (l & 15);
        float v;
        if (k < 512) {
            const int i = k >> 3, t = k & 7;
            v = coef[(i * 64 + j) * 8 + t] * ssp[i * 64 + j];
        } else {
            v = sb[(k - 512) * 64 + j];
        }
        W1f[idx] = f2bf(v);
    } else if (idx < 45056) {
        const int f = idx - 36864;
        const int e = f & 7, l = (f >> 3) & 63, c = (f >> 9) & 3, s = f >> 11;
        const int k = s * 32 + ((l >> 4) << 3) + e;
        const int j = (c << 4) + (l & 15);
        W2f[f] = f2bf(f2w[j * 64 + k]);
    }
}

// ---------------------------------------------------------------------------
// K3: fused KAN + f2 + gate via bf16 MFMA. 32 tokens/block, 256 threads.
// Phase 1: each thread (fixed i = tid&63, 8 tokens) computes fp32 B-spline
// basis + silu, packs bf16 A-fragments into LDS (lane^(s&7) XOR spread).
// Phase 2: per wave, col-tile c = wave id; 18+2 K-steps of 16x16x32 MFMA.
// Same k-map (l>>4)*8+e used for A and B => any bijection is correct.
// Epilogue: y = (x1+kb)*(x2+f2b) written in-place (NHWC).
// ---------------------------------------------------------------------------
__global__ __launch_bounds__(256) void k_kan_mfma(
    float* __restrict__ xdio, const short* __restrict__ W1f,
    const short* __restrict__ W2f, const float* __restrict__ kb,
    const float* __restrict__ f2b)
{
    __shared__ __align__(16) short As1[2 * 18 * 64 * 8];  // 36 KB
    __shared__ __align__(16) short As2[2 * 2 * 64 * 8];   //  4 KB
    const int tid = threadIdx.x;
    const size_t bbase = (size_t)blockIdx.x * 2048;
    const int i = tid & 63;
    const int t0 = tid >> 6;

#pragma unroll 1
    for (int kk = 0; kk < 8; ++kk) {
        const int tk = t0 + 4 * kk;
        const float v = xdio[bbase + tk * 64 + i];

        // degree-3 B-spline basis, knots t[q] = (q-3)*0.4 - 1
        float Bl[11];
#pragma unroll
        for (int q = 0; q < 11; ++q) {
            float ta = (q - 3) * 0.4f - 1.0f;
            float tb = (q - 2) * 0.4f - 1.0f;
            Bl[q] = (v >= ta && v < tb) ? 1.0f : 0.0f;
        }
#pragma unroll
        for (int p = 1; p <= 3; ++p) {
            const float inv = 1.0f / (0.4f * p);
#pragma unroll
            for (int q = 0; q < 11 - p; ++q) {
                float tq = (q - 3) * 0.4f - 1.0f;
                float tqp1 = (q + p - 2) * 0.4f - 1.0f;
                Bl[q] = (v - tq) * inv * Bl[q] + (tqp1 - v) * inv * Bl[q + 1];
            }
        }
        // spline fragment: k = i*8+t -> s = i>>2, group g = i&3, e = t
        {
            const int s = i >> 2;
            const int slot = ((i & 3) << 4) | (tk & 15);
            const int phys = slot ^ (s & 7);
            short8v pk;
#pragma unroll
            for (int t = 0; t < NB; ++t) pk[t] = f2bf(Bl[t]);
            *(short8v*)&As1[(((tk >> 4) * 18 + s) * 64 + phys) * 8] = pk;
        }
        // silu (k = 512+i) and v (A2, k = i): scattered 2B stores
        {
            const float sl = v / (1.0f + expf(-v));
            const int g = (i >> 3) & 3;
            const int slot = (g << 4) | (tk & 15);
            const int e = i & 7;
            const int s2 = 16 + (i >> 5);
            As1[((((tk >> 4) * 18 + s2) * 64 + (slot ^ (s2 & 7)))) * 8 + e] = f2bf(sl);
            const int s3 = i >> 5;
            As2[((((tk >> 4) * 2 + s3) * 64 + (slot ^ (s3 & 7)))) * 8 + e] = f2bf(v);
        }
    }
    __syncthreads();

    const int c = tid >> 6;   // col-tile per wave
    const int l = tid & 63;
    f32x4 accA0 = {0.f, 0.f, 0.f, 0.f}, accA1 = {0.f, 0.f, 0.f, 0.f};
    f32x4 accB0 = {0.f, 0.f, 0.f, 0.f}, accB1 = {0.f, 0.f, 0.f, 0.f};

#pragma unroll 1
    for (int s = 0; s < 18; ++s) {
        const short8v b = *(const short8v*)&W1f[((s * 4 + c) * 64 + l) * 8];
        const short8v a0 = *(const short8v*)&As1[((0 * 18 + s) * 64 + (l ^ (s & 7))) * 8];
        const short8v a1 = *(const short8v*)&As1[((1 * 18 + s) * 64 + (l ^ (s & 7))) * 8];
        accA0 = __builtin_amdgcn_mfma_f32_16x16x32_bf16(a0, b, accA0, 0, 0, 0);
        accA1 = __builtin_amdgcn_mfma_f32_16x16x32_bf16(a1, b, accA1, 0, 0, 0);
    }
#pragma unroll
    for (int s = 0; s < 2; ++s) {
        const short8v b = *(const short8v*)&W2f[((s * 4 + c) * 64 + l) * 8];
        const short8v a0 = *(const short8v*)&As2[((0 * 2 + s) * 64 + (l ^ s)) * 8];
        const short8v a1 = *(const short8v*)&As2[((1 * 2 + s) * 64 + (l ^ s)) * 8];
        accB0 = __builtin_amdgcn_mfma_f32_16x16x32_bf16(a0, b, accB0, 0, 0, 0);
        accB1 = __builtin_amdgcn_mfma_f32_16x16x32_bf16(a1, b, accB1, 0, 0, 0);
    }

    // epilogue: C layout col = lane&15, row = (lane>>4)*4 + reg
    const int j = c * 16 + (l & 15);
    const float kbj = kb[j], f2bj = f2b[j];
    const int rb = (l >> 4) * 4;
#pragma unroll
    for (int reg = 0; reg < 4; ++reg) {
        const int tk0 = rb + reg;
        const float x1a = accA0[reg] + kbj, x2a = accB0[reg] + f2bj;
        xdio[bbase + tk0 * 64 + j] = x1a * x2a;
        const int tk1 = 16 + rb + reg;
        const float x1b = accA1[reg] + kbj, x2b = accB1[reg] + f2bj;
        xdio[bbase + tk1 * 64 + j] = x1b * x2b;
    }
}

// ---------------------------------------------------------------------------
// K4: g 1x1 conv + BN. (unchanged from round 1)
// ---------------------------------------------------------------------------
__global__ __launch_bounds__(256) void k_gbn(
    const float* __restrict__ y, const float* __restrict__ wgt,
    const float* __restrict__ bias, const float* __restrict__ bg,
    const float* __restrict__ bb, const float* __restrict__ bm,
    const float* __restrict__ bv, float* __restrict__ z)
{
    __shared__ float ys[WW][CD + 1];
    const int bh = blockIdx.x;
    const int b = bh >> 6, h = bh & 63;
    const float* yrow = y + (size_t)bh * WW * CD;
    for (int i = threadIdx.x; i < WW * CD; i += 256)
        ys[i >> 6][i & 63] = yrow[i];
    __syncthreads();
    const int w = threadIdx.x & 63;
    const int o0 = (threadIdx.x >> 6) * 16;
    float acc[16];
#pragma unroll
    for (int k = 0; k < 16; ++k) acc[k] = bias[o0 + k];
    for (int i = 0; i < CD; i += 4) {
        float y0 = ys[w][i], y1 = ys[w][i + 1], y2 = ys[w][i + 2], y3 = ys[w][i + 3];
#pragma unroll
        for (int k = 0; k < 16; ++k) {
            const float4 wv = *(const float4*)(wgt + (o0 + k) * CD + i);
            acc[k] = fmaf(y0, wv.x, fmaf(y1, wv.y, fmaf(y2, wv.z, fmaf(y3, wv.w, acc[k]))));
        }
    }
    float* op = z + (size_t)b * CD * PLANE + h * WW + w;
#pragma unroll
    for (int k = 0; k < 16; ++k) {
        int o = o0 + k;
        float inv = rsqrtf(bv[o] + BN_EPS);
        op[(size_t)o * PLANE] = bg[o] * (acc[k] - bm[o]) * inv + bb[o];
    }
}

// ---------------------------------------------------------------------------
// K5: 7x7 depthwise conv + bias + residual add -> d_out. (unchanged)
// ---------------------------------------------------------------------------
__global__ __launch_bounds__(256) void k_dw2(
    const float* __restrict__ z, const float* __restrict__ wgt,
    const float* __restrict__ bias, const float* __restrict__ inp,
    float* __restrict__ out)
{
    const int bh = blockIdx.x;
    const int b = bh >> 6, h = bh & 63;
    const int w = threadIdx.x & 63;
    const int c0 = (threadIdx.x >> 6) * 16;
    const float* base = z + (size_t)b * CD * PLANE;
#pragma unroll 1
    for (int k = 0; k < 16; ++k) {
        const int c = c0 + k;
        const float* wp = wgt + c * 49;
        float acc = bias[c];
#pragma unroll
        for (int dy = 0; dy < 7; ++dy) {
            const int hy = h + dy - 3;
            if (hy < 0 || hy >= HH) continue;
            const float* rp = base + (size_t)c * PLANE + hy * WW;
#pragma unroll
            for (int dx = 0; dx < 7; ++dx) {
                const int wx = w + dx - 3;
                float xv = (wx >= 0 && wx < WW) ? rp[wx] : 0.f;
                acc = fmaf(xv, wp[dy * 7 + dx], acc);
            }
        }
        size_t oi = ((size_t)b * CD + c) * PLANE + h * WW + w;
        out[oi] = inp[oi] + acc;
    }
}

// ---------------------------------------------------------------------------
extern "C" void kernel_launch(void* const* d_in, const int* in_sizes, int n_in,
                              void* d_out, int out_size, void* d_ws, size_t ws_size,
                              hipStream_t stream)
{
    (void)in_sizes; (void)n_in; (void)out_size; (void)ws_size;
    const float* x        = (const float*)d_in[0];
    const float* reduce_w = (const float*)d_in[1];
    const float* reduce_b = (const float*)d_in[2];
    const float* dw_w     = (const float*)d_in[3];
    const float* dw_b     = (const float*)d_in[4];
    const float* dw_g     = (const float*)d_in[5];
    const float* dw_beta  = (const float*)d_in[6];
    const float* dw_m     = (const float*)d_in[7];
    const float* dw_v     = (const float*)d_in[8];
    const float* f2_w     = (const float*)d_in[9];
    const float* f2_b     = (const float*)d_in[10];
    const float* coef     = (const float*)d_in[11];
    const float* sbase    = (const float*)d_in[12];
    const float* ssp      = (const float*)d_in[13];
    const float* kbias    = (const float*)d_in[14];
    const float* g_w      = (const float*)d_in[15];
    const float* g_b      = (const float*)d_in[16];
    const float* g_g      = (const float*)d_in[17];
    const float* g_beta   = (const float*)d_in[18];
    const float* g_m      = (const float*)d_in[19];
    const float* g_v      = (const float*)d_in[20];
    const float* dw2_w    = (const float*)d_in[21];
    const float* dw2_b    = (const float*)d_in[22];
    float* out = (float*)d_out;

    // ws layout: W1f (36864 sh) | W2f (8192 sh) | pad | 3x NEL floats
    const size_t NEL = (size_t)BSZ * CD * PLANE;
    short* W1f = (short*)d_ws;
    short* W2f = W1f + 36864;
    float* inp = (float*)((char*)d_ws + 92160);  // 45056*2 -> pad to 92160 (16B aligned)
    float* xd  = inp + NEL;
    float* z   = xd + NEL;

    k_prep<<<176, 256, 0, stream>>>(coef, ssp, sbase, f2_w, W1f, W2f);
    k_reduce<<<BSZ * HH, 256, 0, stream>>>(x, reduce_w, reduce_b, inp);
    k_dwbn<<<BSZ * HH, 256, 0, stream>>>(inp, dw_w, dw_b, dw_g, dw_beta, dw_m, dw_v, xd);
    k_kan_mfma<<<NPIX / 32, 256, 0, stream>>>(xd, W1f, W2f, kbias, f2_b);
    k_gbn<<<BSZ * HH, 256, 0, stream>>>(xd, g_w, g_b, g_g, g_beta, g_m, g_v, z);
    k_dw2<<<BSZ * HH, 256, 0, stream>>>(z, dw2_w, dw2_b, inp, out);
}

// Round 3
// 151.126 us; speedup vs baseline: 9.7629x; 3.3868x over previous
//
#include <hip/hip_runtime.h>
#include <hip/hip_bf16.h>

#define BSZ 32
#define CIN 128
#define CD 64
#define HH 64
#define WW 64
#define PLANE (HH * WW)
#define NPIX (BSZ * HH * WW)
#define NB 8
#define BN_EPS 1e-5f

typedef __attribute__((ext_vector_type(8))) short short8v;
typedef __attribute__((ext_vector_type(4))) float f32x4;

static __device__ __forceinline__ short f2bf(float f) {
    __hip_bfloat16 h = __float2bfloat16(f);
    return __builtin_bit_cast(short, h);
}

// ---------------------------------------------------------------------------
// K0: prepack all matmul weights into MFMA B-fragment order (bf16) + fold BN.
// Fragment layout (verified round 2): element ((s*4+c)*64+l)*8+e holds
// W[k = s*32 + (l>>4)*8 + e][j = c*16 + (l&15)].
// W1f[576x64]: KAN spline(coef*ssp, k=i*8+t) rows 0..511, silu(scale_base)
// rows 512..575. W2f[64x64]=f2w^T. WRf[128x64]=reduce_w^T. WGf[64x64]=g_w^T.
// cbuf: [0:64) dw-BN scale, [64:128) dw-BN shift, [128:192) g-BN scale,
// [192:256) g-BN shift.
// ---------------------------------------------------------------------------
__global__ __launch_bounds__(256) void k_prep(
    const float* __restrict__ coef, const float* __restrict__ ssp,
    const float* __restrict__ sb, const float* __restrict__ f2w,
    const float* __restrict__ reduce_w, const float* __restrict__ g_w,
    const float* __restrict__ dw_g, const float* __restrict__ dw_beta,
    const float* __restrict__ dw_m, const float* __restrict__ dw_v,
    const float* __restrict__ dw_b, const float* __restrict__ g_g,
    const float* __restrict__ g_beta, const float* __restrict__ g_m,
    const float* __restrict__ g_v, const float* __restrict__ g_b,
    short* __restrict__ W1f, short* __restrict__ W2f,
    short* __restrict__ WRf, short* __restrict__ WGf,
    float* __restrict__ cbuf)
{
    const int idx = blockIdx.x * 256 + threadIdx.x;
    if (idx < 36864) {
        const int e = idx & 7, l = (idx >> 3) & 63, c = (idx >> 9) & 3, s = idx >> 11;
        const int k = s * 32 + ((l >> 4) << 3) + e;
        const int j = (c << 4) + (l & 15);
        float v;
        if (k < 512) {
            const int i = k >> 3, t = k & 7;
            v = coef[(i * 64 + j) * 8 + t] * ssp[i * 64 + j];
        } else {
            v = sb[(k - 512) * 64 + j];
        }
        W1f[idx] = f2bf(v);
    } else if (idx < 45056) {
        const int f = idx - 36864;
        const int e = f & 7, l = (f >> 3) & 63, c = (f >> 9) & 3, s = f >> 11;
        const int k = s * 32 + ((l >> 4) << 3) + e;
        const int j = (c << 4) + (l & 15);
        W2f[f] = f2bf(f2w[j * 64 + k]);
    } else if (idx < 53248) {
        const int f = idx - 45056;
        const int e = f & 7, l = (f >> 3) & 63, c = (f >> 9) & 3, s = f >> 11;
        const int k = s * 32 + ((l >> 4) << 3) + e;
        const int j = (c << 4) + (l & 15);
        WRf[f] = f2bf(reduce_w[j * CIN + k]);
    } else if (idx < 57344) {
        const int f = idx - 53248;
        const int e = f & 7, l = (f >> 3) & 63, c = (f >> 9) & 3, s = f >> 11;
        const int k = s * 32 + ((l >> 4) << 3) + e;
        const int j = (c << 4) + (l & 15);
        WGf[f] = f2bf(g_w[j * 64 + k]);
    } else if (idx < 57600) {
        const int q = (idx - 57344) >> 6, c = idx & 63;
        if (q == 0) cbuf[c] = dw_g[c] * rsqrtf(dw_v[c] + BN_EPS);
        else if (q == 1) {
            float sc = dw_g[c] * rsqrtf(dw_v[c] + BN_EPS);
            cbuf[64 + c] = (dw_b[c] - dw_m[c]) * sc + dw_beta[c];
        } else if (q == 2) cbuf[128 + c] = g_g[c] * rsqrtf(g_v[c] + BN_EPS);
        else {
            float sc = g_g[c] * rsqrtf(g_v[c] + BN_EPS);
            cbuf[192 + c] = (g_b[c] - g_m[c]) * sc + g_beta[c];
        }
    }
}

// ---------------------------------------------------------------------------
// K1: 1x1 conv 128->64 via MFMA. Block = (b, h-pair) = 128 tokens.
// Stage A[8 mt][4 s][64 l][8 e] bf16 in LDS, 32 MFMAs/wave (wave = j-tile),
// epilogue via padded LDS transpose -> NCHW coalesced.
// ---------------------------------------------------------------------------
__global__ __launch_bounds__(256) void k_reduce_mfma(
    const float* __restrict__ x, const short* __restrict__ WRf,
    const float* __restrict__ bias, float* __restrict__ out)
{
    __shared__ __align__(16) char smem[34048];  // A 32KB bf16 / Osh 64*133*4
    short* As = (short*)smem;
    float* Osh = (float*)smem;
    const int bid = blockIdx.x;
    const int b = bid >> 5, h0 = (bid & 31) * 2;
    const int tid = threadIdx.x;
    const float* xb = x + (size_t)b * CIN * PLANE + h0 * WW;
#pragma unroll 1
    for (int p = 0; p < 64; ++p) {
        const int idx = tid + (p << 8);
        const int c = idx >> 7, rt = idx & 127;   // rt = token (2 rows contig)
        const float v = xb[(size_t)c * PLANE + rt];
        const int s = c >> 5, g = (c >> 3) & 3, e = c & 7;
        const int mt = rt >> 4, m = rt & 15;
        As[((mt * 4 + s) * 64 + (((g << 4) | m) ^ (s & 7))) * 8 + e] = f2bf(v);
    }
    __syncthreads();
    const int cw = tid >> 6, l = tid & 63;
    f32x4 acc[8];
#pragma unroll
    for (int i = 0; i < 8; ++i) acc[i] = (f32x4){0.f, 0.f, 0.f, 0.f};
#pragma unroll 1
    for (int s = 0; s < 4; ++s) {
        const short8v bfr = *(const short8v*)&WRf[((s * 4 + cw) * 64 + l) * 8];
        const int lx = l ^ (s & 7);
#pragma unroll
        for (int mt = 0; mt < 8; ++mt) {
            const short8v a = *(const short8v*)&As[((mt * 4 + s) * 64 + lx) * 8];
            acc[mt] = __builtin_amdgcn_mfma_f32_16x16x32_bf16(a, bfr, acc[mt], 0, 0, 0);
        }
    }
    __syncthreads();
    const int j = (cw << 4) + (l & 15);
    const float bj = bias[j];
    const int rb = (l >> 4) << 2;
#pragma unroll
    for (int mt = 0; mt < 8; ++mt)
#pragma unroll
        for (int r = 0; r < 4; ++r)
            Osh[j * 133 + mt * 16 + rb + r] = acc[mt][r] + bj;
    __syncthreads();
    float* ob = out + (size_t)b * CD * PLANE + h0 * WW;
#pragma unroll 1
    for (int p = 0; p < 32; ++p) {
        const int idx = tid + (p << 8);
        const int jj = idx >> 7, rt = idx & 127;
        ob[(size_t)jj * PLANE + rt] = Osh[jj * 133 + rt];
    }
}

// ---------------------------------------------------------------------------
// K2/K5: 7x7 depthwise conv, register-streaming. Wave = one channel
// half-plane, lane = w. Rolling 7-row window; w-shifts via __shfl (DS pipe);
// 49 FMA per output row; compile-time ring indices (full unroll).
// RESID=false: BN epilogue (scale/shift). RESID=true: +bias +residual.
// ---------------------------------------------------------------------------
template<int H0, bool RESID>
__device__ __forceinline__ void dw_half(
    const float* __restrict__ plane, const float (&K)[49],
    float scl, float shf, const float* __restrict__ rplane,
    float* __restrict__ oplane, int lane)
{
    float acc[7] = {0.f, 0.f, 0.f, 0.f, 0.f, 0.f, 0.f};
#pragma unroll
    for (int r = 0; r < 38; ++r) {
        const int ra = H0 + r - 3;          // input row (compile-time)
        float rowv = 0.f;
        if (ra >= 0 && ra < 64) rowv = plane[ra * 64 + lane];
        float sh[7];
        sh[3] = rowv;
#pragma unroll
        for (int d = 1; d <= 3; ++d) {
            float tp = __shfl(rowv, lane + d);
            sh[3 + d] = (lane + d < 64) ? tp : 0.f;
            float tm = __shfl(rowv, lane - d);
            sh[3 - d] = (lane - d >= 0) ? tm : 0.f;
        }
#pragma unroll
        for (int dy = 0; dy < 7; ++dy) {
            const int h = ra + 3 - dy;      // output row fed by this input row
            if (h >= H0 && h < H0 + 32 && h < 64) {
                const int slot = (h - H0) % 7;
#pragma unroll
                for (int dx = 0; dx < 7; ++dx)
                    acc[slot] = fmaf(sh[dx], K[dy * 7 + dx], acc[slot]);
            }
        }
        const int hd = ra - 3;              // output row completed this step
        if (hd >= H0 && hd < H0 + 32) {
            const int slot = (hd - H0) % 7;
            float val;
            if (RESID) val = acc[slot] + shf + rplane[hd * 64 + lane];
            else       val = acc[slot] * scl + shf;
            oplane[hd * 64 + lane] = val;
            acc[slot] = 0.f;
        }
    }
}

template<bool RESID>
__global__ __launch_bounds__(256) void k_dwconv(
    const float* __restrict__ in, const float* __restrict__ filt,
    const float* __restrict__ sc, const float* __restrict__ shv,
    const float* __restrict__ resid, float* __restrict__ out)
{
    const int bid = blockIdx.x;
    const int b = bid >> 5, c4 = (bid >> 1) & 15, half = bid & 1;
    const int c = c4 * 4 + (threadIdx.x >> 6);
    const int lane = threadIdx.x & 63;
    const size_t pbase = ((size_t)b * CD + c) * PLANE;
    const float* plane = in + pbase;
    const float* wp = filt + c * 49;
    float K[49];
#pragma unroll
    for (int q = 0; q < 49; ++q) K[q] = wp[q];
    const float scl = RESID ? 1.f : sc[c];
    const float shf = shv[c];
    const float* rplane = RESID ? (resid + pbase) : nullptr;
    float* oplane = out + pbase;
    if (half == 0) dw_half<0, RESID>(plane, K, scl, shf, rplane, oplane, lane);
    else           dw_half<32, RESID>(plane, K, scl, shf, rplane, oplane, lane);
}

// ---------------------------------------------------------------------------
// K3: fused KAN + f2 + gate via bf16 MFMA, NCHW in-place. 32 tokens/block.
// Staging: thread (token = tid&31, c = pass*8 + tid>>5) computes fp32 basis
// + silu, packs bf16 A-fragments to LDS. MFMA: wave = j-tile, 18+2 K-steps.
// Epilogue: y=(x1+kb)*(x2+f2b) through padded LDS -> NCHW coalesced.
// ---------------------------------------------------------------------------
__global__ __launch_bounds__(256) void k_kan_mfma(
    float* __restrict__ xdio, const short* __restrict__ W1f,
    const short* __restrict__ W2f, const float* __restrict__ kb,
    const float* __restrict__ f2b)
{
    __shared__ __align__(16) short As1[2 * 18 * 64 * 8];  // 36 KB
    __shared__ __align__(16) short As2[2 * 2 * 64 * 8];   //  4 KB
    const int tid = threadIdx.x;
    const int tg0 = blockIdx.x * 32;
    const int b = tg0 >> 12, pix0 = tg0 & 4095;
    float* xb = xdio + (size_t)b * CD * PLANE + pix0;
    const int tkn = tid & 31;
    const int mt = tkn >> 4, m = tkn & 15;

#pragma unroll 1
    for (int p = 0; p < 8; ++p) {
        const int c = p * 8 + (tid >> 5);
        const float v = xb[(size_t)c * PLANE + tkn];

        // degree-3 B-spline basis, knots t[q] = (q-3)*0.4 - 1
        float Bl[11];
#pragma unroll
        for (int q = 0; q < 11; ++q) {
            float ta = (q - 3) * 0.4f - 1.0f;
            float tb = (q - 2) * 0.4f - 1.0f;
            Bl[q] = (v >= ta && v < tb) ? 1.0f : 0.0f;
        }
#pragma unroll
        for (int pp = 1; pp <= 3; ++pp) {
            const float inv = 1.0f / (0.4f * pp);
#pragma unroll
            for (int q = 0; q < 11 - pp; ++q) {
                float tq = (q - 3) * 0.4f - 1.0f;
                float tqp1 = (q + pp - 2) * 0.4f - 1.0f;
                Bl[q] = (v - tq) * inv * Bl[q] + (tqp1 - v) * inv * Bl[q + 1];
            }
        }
        {   // spline rows: k = c*8+t -> s = c>>2, g = c&3, e = t
            const int s = c >> 2;
            const int phys = (((c & 3) << 4) | m) ^ (s & 7);
            short8v pk;
#pragma unroll
            for (int t = 0; t < NB; ++t) pk[t] = f2bf(Bl[t]);
            *(short8v*)&As1[((mt * 18 + s) * 64 + phys) * 8] = pk;
        }
        {   // silu row k=512+c and raw-v (A2, k=c)
            const float sl = v / (1.0f + expf(-v));
            const int g2 = (c >> 3) & 3, e = c & 7;
            const int s2 = 16 + (c >> 5);
            As1[((mt * 18 + s2) * 64 + ((((g2 << 4) | m)) ^ (s2 & 7))) * 8 + e] = f2bf(sl);
            const int s3 = c >> 5;
            As2[((mt * 2 + s3) * 64 + ((((g2 << 4) | m)) ^ (s3 & 7))) * 8 + e] = f2bf(v);
        }
    }
    __syncthreads();

    const int cw = tid >> 6, l = tid & 63;
    f32x4 accA0 = {0.f,0.f,0.f,0.f}, accA1 = {0.f,0.f,0.f,0.f};
    f32x4 accB0 = {0.f,0.f,0.f,0.f}, accB1 = {0.f,0.f,0.f,0.f};
#pragma unroll 1
    for (int s = 0; s < 18; ++s) {
        const short8v bfr = *(const short8v*)&W1f[((s * 4 + cw) * 64 + l) * 8];
        const short8v a0 = *(const short8v*)&As1[((0 * 18 + s) * 64 + (l ^ (s & 7))) * 8];
        const short8v a1 = *(const short8v*)&As1[((1 * 18 + s) * 64 + (l ^ (s & 7))) * 8];
        accA0 = __builtin_amdgcn_mfma_f32_16x16x32_bf16(a0, bfr, accA0, 0, 0, 0);
        accA1 = __builtin_amdgcn_mfma_f32_16x16x32_bf16(a1, bfr, accA1, 0, 0, 0);
    }
#pragma unroll
    for (int s = 0; s < 2; ++s) {
        const short8v bfr = *(const short8v*)&W2f[((s * 4 + cw) * 64 + l) * 8];
        const short8v a0 = *(const short8v*)&As2[((0 * 2 + s) * 64 + (l ^ s)) * 8];
        const short8v a1 = *(const short8v*)&As2[((1 * 2 + s) * 64 + (l ^ s)) * 8];
        accB0 = __builtin_amdgcn_mfma_f32_16x16x32_bf16(a0, bfr, accB0, 0, 0, 0);
        accB1 = __builtin_amdgcn_mfma_f32_16x16x32_bf16(a1, bfr, accB1, 0, 0, 0);
    }
    __syncthreads();

    float* Osh = (float*)As1;   // 64 j x 33 tokens (padded), 8.4 KB
    const int j = (cw << 4) + (l & 15);
    const float kbj = kb[j], f2bj = f2b[j];
    const int rb = (l >> 4) << 2;
#pragma unroll
    for (int r = 0; r < 4; ++r) {
        Osh[j * 33 + rb + r]      = (accA0[r] + kbj) * (accB0[r] + f2bj);
        Osh[j * 33 + 16 + rb + r] = (accA1[r] + kbj) * (accB1[r] + f2bj);
    }
    __syncthreads();
#pragma unroll
    for (int q = 0; q < 8; ++q) {
        const int idx = tid + (q << 8);
        const int jj = idx >> 5, t2 = idx & 31;
        xb[(size_t)jj * PLANE + t2] = Osh[jj * 33 + t2];
    }
}

// ---------------------------------------------------------------------------
// K4: g 1x1 conv 64->64 + folded BN via MFMA. Same structure as K1, K=64.
// ---------------------------------------------------------------------------
__global__ __launch_bounds__(256) void k_gbn_mfma(
    const float* __restrict__ y, const short* __restrict__ WGf,
    const float* __restrict__ gs, const float* __restrict__ gsh,
    float* __restrict__ z)
{
    __shared__ __align__(16) char smem[34048];
    short* As = (short*)smem;
    float* Osh = (float*)smem;
    const int bid = blockIdx.x;
    const int b = bid >> 5, h0 = (bid & 31) * 2;
    const int tid = threadIdx.x;
    const float* yb = y + (size_t)b * CD * PLANE + h0 * WW;
#pragma unroll 1
    for (int p = 0; p < 32; ++p) {
        const int idx = tid + (p << 8);
        const int c = idx >> 7, rt = idx & 127;
        const float v = yb[(size_t)c * PLANE + rt];
        const int s = c >> 5, g = (c >> 3) & 3, e = c & 7;
        const int mt = rt >> 4, m = rt & 15;
        As[((mt * 2 + s) * 64 + (((g << 4) | m) ^ (s & 7))) * 8 + e] = f2bf(v);
    }
    __syncthreads();
    const int cw = tid >> 6, l = tid & 63;
    f32x4 acc[8];
#pragma unroll
    for (int i = 0; i < 8; ++i) acc[i] = (f32x4){0.f, 0.f, 0.f, 0.f};
#pragma unroll
    for (int s = 0; s < 2; ++s) {
        const short8v bfr = *(const short8v*)&WGf[((s * 4 + cw) * 64 + l) * 8];
        const int lx = l ^ (s & 7);
#pragma unroll
        for (int mt = 0; mt < 8; ++mt) {
            const short8v a = *(const short8v*)&As[((mt * 2 + s) * 64 + lx) * 8];
            acc[mt] = __builtin_amdgcn_mfma_f32_16x16x32_bf16(a, bfr, acc[mt], 0, 0, 0);
        }
    }
    __syncthreads();
    const int j = (cw << 4) + (l & 15);
    const float sj = gs[j], hj = gsh[j];
    const int rb = (l >> 4) << 2;
#pragma unroll
    for (int mt = 0; mt < 8; ++mt)
#pragma unroll
        for (int r = 0; r < 4; ++r)
            Osh[j * 133 + mt * 16 + rb + r] = acc[mt][r] * sj + hj;
    __syncthreads();
    float* zb = z + (size_t)b * CD * PLANE + h0 * WW;
#pragma unroll 1
    for (int p = 0; p < 32; ++p) {
        const int idx = tid + (p << 8);
        const int jj = idx >> 7, rt = idx & 127;
        zb[(size_t)jj * PLANE + rt] = Osh[jj * 133 + rt];
    }
}

// ---------------------------------------------------------------------------
extern "C" void kernel_launch(void* const* d_in, const int* in_sizes, int n_in,
                              void* d_out, int out_size, void* d_ws, size_t ws_size,
                              hipStream_t stream)
{
    (void)in_sizes; (void)n_in; (void)out_size; (void)ws_size;
    const float* x        = (const float*)d_in[0];
    const float* reduce_w = (const float*)d_in[1];
    const float* reduce_b = (const float*)d_in[2];
    const float* dw_w     = (const float*)d_in[3];
    const float* dw_b     = (const float*)d_in[4];
    const float* dw_g     = (const float*)d_in[5];
    const float* dw_beta  = (const float*)d_in[6];
    const float* dw_m     = (const float*)d_in[7];
    const float* dw_v     = (const float*)d_in[8];
    const float* f2_w     = (const float*)d_in[9];
    const float* f2_b     = (const float*)d_in[10];
    const float* coef     = (const float*)d_in[11];
    const float* sbase    = (const float*)d_in[12];
    const float* ssp      = (const float*)d_in[13];
    const float* kbias    = (const float*)d_in[14];
    const float* g_w      = (const float*)d_in[15];
    const float* g_b      = (const float*)d_in[16];
    const float* g_g      = (const float*)d_in[17];
    const float* g_beta   = (const float*)d_in[18];
    const float* g_m      = (const float*)d_in[19];
    const float* g_v      = (const float*)d_in[20];
    const float* dw2_w    = (const float*)d_in[21];
    const float* dw2_b    = (const float*)d_in[22];
    float* out = (float*)d_out;

    // ws: W1f 36864sh | W2f 8192sh | WRf 8192sh | WGf 4096sh | cbuf 256f
    //     | pad to 128KB | inp 32MB | xd 32MB | z 32MB
    const size_t NEL = (size_t)BSZ * CD * PLANE;
    short* W1f = (short*)d_ws;
    short* W2f = W1f + 36864;
    short* WRf = W2f + 8192;
    short* WGf = WRf + 8192;
    float* cbuf = (float*)((char*)d_ws + 115200);
    float* inp = (float*)((char*)d_ws + 131072);
    float* xd  = inp + NEL;
    float* z   = xd + NEL;

    k_prep<<<225, 256, 0, stream>>>(coef, ssp, sbase, f2_w, reduce_w, g_w,
                                    dw_g, dw_beta, dw_m, dw_v, dw_b,
                                    g_g, g_beta, g_m, g_v, g_b,
                                    W1f, W2f, WRf, WGf, cbuf);
    k_reduce_mfma<<<BSZ * 32, 256, 0, stream>>>(x, WRf, reduce_b, inp);
    k_dwconv<false><<<BSZ * 16 * 2, 256, 0, stream>>>(inp, dw_w, cbuf, cbuf + 64, nullptr, xd);
    k_kan_mfma<<<NPIX / 32, 256, 0, stream>>>(xd, W1f, W2f, kbias, f2_b);
    k_gbn_mfma<<<BSZ * 32, 256, 0, stream>>>(xd, WGf, cbuf + 128, cbuf + 192, z);
    k_dwconv<true><<<BSZ * 16 * 2, 256, 0, stream>>>(z, dw2_w, nullptr, dw2_b, inp, out);
}

// Round 4
// 122.611 us; speedup vs baseline: 12.0334x; 1.2326x over previous
//
#include <hip/hip_runtime.h>
#include <hip/hip_bf16.h>

#define BSZ 32
#define CIN 128
#define CD 64
#define HH 64
#define WW 64
#define PLANE (HH * WW)
#define NPIX (BSZ * HH * WW)
#define NB 8
#define BN_EPS 1e-5f

typedef __attribute__((ext_vector_type(8))) short short8v;
typedef __attribute__((ext_vector_type(4))) float f32x4;
typedef __attribute__((ext_vector_type(4))) unsigned int u32x4;

static __device__ __forceinline__ short f2bf(float f) {
    __hip_bfloat16 h = __float2bfloat16(f);
    return __builtin_bit_cast(short, h);
}
static __device__ __forceinline__ unsigned int pk2bf(float a, float b) {
    unsigned int lo = (unsigned short)__builtin_bit_cast(short, __float2bfloat16(a));
    unsigned int hi = (unsigned short)__builtin_bit_cast(short, __float2bfloat16(b));
    return lo | (hi << 16);
}

// ---------------------------------------------------------------------------
// K0: prepack all matmul weights into MFMA B-fragment order (bf16) + fold BN.
// Fragment layout (verified round 2): element ((s*4+c)*64+l)*8+e holds
// W[k = s*32 + (l>>4)*8 + e][j = c*16 + (l&15)].
// ---------------------------------------------------------------------------
__global__ __launch_bounds__(256) void k_prep(
    const float* __restrict__ coef, const float* __restrict__ ssp,
    const float* __restrict__ sb, const float* __restrict__ f2w,
    const float* __restrict__ reduce_w, const float* __restrict__ g_w,
    const float* __restrict__ dw_g, const float* __restrict__ dw_beta,
    const float* __restrict__ dw_m, const float* __restrict__ dw_v,
    const float* __restrict__ dw_b, const float* __restrict__ g_g,
    const float* __restrict__ g_beta, const float* __restrict__ g_m,
    const float* __restrict__ g_v, const float* __restrict__ g_b,
    short* __restrict__ W1f, short* __restrict__ W2f,
    short* __restrict__ WRf, short* __restrict__ WGf,
    float* __restrict__ cbuf)
{
    const int idx = blockIdx.x * 256 + threadIdx.x;
    if (idx < 36864) {
        const int e = idx & 7, l = (idx >> 3) & 63, c = (idx >> 9) & 3, s = idx >> 11;
        const int k = s * 32 + ((l >> 4) << 3) + e;
        const int j = (c << 4) + (l & 15);
        float v;
        if (k < 512) {
            const int i = k >> 3, t = k & 7;
            v = coef[(i * 64 + j) * 8 + t] * ssp[i * 64 + j];
        } else {
            v = sb[(k - 512) * 64 + j];
        }
        W1f[idx] = f2bf(v);
    } else if (idx < 45056) {
        const int f = idx - 36864;
        const int e = f & 7, l = (f >> 3) & 63, c = (f >> 9) & 3, s = f >> 11;
        const int k = s * 32 + ((l >> 4) << 3) + e;
        const int j = (c << 4) + (l & 15);
        W2f[f] = f2bf(f2w[j * 64 + k]);
    } else if (idx < 53248) {
        const int f = idx - 45056;
        const int e = f & 7, l = (f >> 3) & 63, c = (f >> 9) & 3, s = f >> 11;
        const int k = s * 32 + ((l >> 4) << 3) + e;
        const int j = (c << 4) + (l & 15);
        WRf[f] = f2bf(reduce_w[j * CIN + k]);
    } else if (idx < 57344) {
        const int f = idx - 53248;
        const int e = f & 7, l = (f >> 3) & 63, c = (f >> 9) & 3, s = f >> 11;
        const int k = s * 32 + ((l >> 4) << 3) + e;
        const int j = (c << 4) + (l & 15);
        WGf[f] = f2bf(g_w[j * 64 + k]);
    } else if (idx < 57600) {
        const int q = (idx - 57344) >> 6, c = idx & 63;
        if (q == 0) cbuf[c] = dw_g[c] * rsqrtf(dw_v[c] + BN_EPS);
        else if (q == 1) {
            float sc = dw_g[c] * rsqrtf(dw_v[c] + BN_EPS);
            cbuf[64 + c] = (dw_b[c] - dw_m[c]) * sc + dw_beta[c];
        } else if (q == 2) cbuf[128 + c] = g_g[c] * rsqrtf(g_v[c] + BN_EPS);
        else {
            float sc = g_g[c] * rsqrtf(g_v[c] + BN_EPS);
            cbuf[192 + c] = (g_b[c] - g_m[c]) * sc + g_beta[c];
        }
    }
}

// ---------------------------------------------------------------------------
// K1: 1x1 conv 128->64 via MFMA. (unchanged from round 3)
// ---------------------------------------------------------------------------
__global__ __launch_bounds__(256) void k_reduce_mfma(
    const float* __restrict__ x, const short* __restrict__ WRf,
    const float* __restrict__ bias, float* __restrict__ out)
{
    __shared__ __align__(16) char smem[34048];
    short* As = (short*)smem;
    float* Osh = (float*)smem;
    const int bid = blockIdx.x;
    const int b = bid >> 5, h0 = (bid & 31) * 2;
    const int tid = threadIdx.x;
    const float* xb = x + (size_t)b * CIN * PLANE + h0 * WW;
#pragma unroll 1
    for (int p = 0; p < 64; ++p) {
        const int idx = tid + (p << 8);
        const int c = idx >> 7, rt = idx & 127;
        const float v = xb[(size_t)c * PLANE + rt];
        const int s = c >> 5, g = (c >> 3) & 3, e = c & 7;
        const int mt = rt >> 4, m = rt & 15;
        As[((mt * 4 + s) * 64 + (((g << 4) | m) ^ (s & 7))) * 8 + e] = f2bf(v);
    }
    __syncthreads();
    const int cw = tid >> 6, l = tid & 63;
    f32x4 acc[8];
#pragma unroll
    for (int i = 0; i < 8; ++i) acc[i] = (f32x4){0.f, 0.f, 0.f, 0.f};
#pragma unroll 1
    for (int s = 0; s < 4; ++s) {
        const short8v bfr = *(const short8v*)&WRf[((s * 4 + cw) * 64 + l) * 8];
        const int lx = l ^ (s & 7);
#pragma unroll
        for (int mt = 0; mt < 8; ++mt) {
            const short8v a = *(const short8v*)&As[((mt * 4 + s) * 64 + lx) * 8];
            acc[mt] = __builtin_amdgcn_mfma_f32_16x16x32_bf16(a, bfr, acc[mt], 0, 0, 0);
        }
    }
    __syncthreads();
    const int j = (cw << 4) + (l & 15);
    const float bj = bias[j];
    const int rb = (l >> 4) << 2;
#pragma unroll
    for (int mt = 0; mt < 8; ++mt)
#pragma unroll
        for (int r = 0; r < 4; ++r)
            Osh[j * 133 + mt * 16 + rb + r] = acc[mt][r] + bj;
    __syncthreads();
    float* ob = out + (size_t)b * CD * PLANE + h0 * WW;
#pragma unroll 1
    for (int p = 0; p < 32; ++p) {
        const int idx = tid + (p << 8);
        const int jj = idx >> 7, rt = idx & 127;
        ob[(size_t)jj * PLANE + rt] = Osh[jj * 133 + rt];
    }
}

// ---------------------------------------------------------------------------
// K2/K5: 7x7 depthwise conv, register-streaming. (unchanged from round 3)
// ---------------------------------------------------------------------------
template<int H0, bool RESID>
__device__ __forceinline__ void dw_half(
    const float* __restrict__ plane, const float (&K)[49],
    float scl, float shf, const float* __restrict__ rplane,
    float* __restrict__ oplane, int lane)
{
    float acc[7] = {0.f, 0.f, 0.f, 0.f, 0.f, 0.f, 0.f};
#pragma unroll
    for (int r = 0; r < 38; ++r) {
        const int ra = H0 + r - 3;
        float rowv = 0.f;
        if (ra >= 0 && ra < 64) rowv = plane[ra * 64 + lane];
        float sh[7];
        sh[3] = rowv;
#pragma unroll
        for (int d = 1; d <= 3; ++d) {
            float tp = __shfl(rowv, lane + d);
            sh[3 + d] = (lane + d < 64) ? tp : 0.f;
            float tm = __shfl(rowv, lane - d);
            sh[3 - d] = (lane - d >= 0) ? tm : 0.f;
        }
#pragma unroll
        for (int dy = 0; dy < 7; ++dy) {
            const int h = ra + 3 - dy;
            if (h >= H0 && h < H0 + 32 && h < 64) {
                const int slot = (h - H0) % 7;
#pragma unroll
                for (int dx = 0; dx < 7; ++dx)
                    acc[slot] = fmaf(sh[dx], K[dy * 7 + dx], acc[slot]);
            }
        }
        const int hd = ra - 3;
        if (hd >= H0 && hd < H0 + 32) {
            const int slot = (hd - H0) % 7;
            float val;
            if (RESID) val = acc[slot] + shf + rplane[hd * 64 + lane];
            else       val = acc[slot] * scl + shf;
            oplane[hd * 64 + lane] = val;
            acc[slot] = 0.f;
        }
    }
}

template<bool RESID>
__global__ __launch_bounds__(256) void k_dwconv(
    const float* __restrict__ in, const float* __restrict__ filt,
    const float* __restrict__ sc, const float* __restrict__ shv,
    const float* __restrict__ resid, float* __restrict__ out)
{
    const int bid = blockIdx.x;
    const int b = bid >> 5, c4 = (bid >> 1) & 15, half = bid & 1;
    const int c = c4 * 4 + (threadIdx.x >> 6);
    const int lane = threadIdx.x & 63;
    const size_t pbase = ((size_t)b * CD + c) * PLANE;
    const float* plane = in + pbase;
    const float* wp = filt + c * 49;
    float K[49];
#pragma unroll
    for (int q = 0; q < 49; ++q) K[q] = wp[q];
    const float scl = RESID ? 1.f : sc[c];
    const float shf = shv[c];
    const float* rplane = RESID ? (resid + pbase) : nullptr;
    float* oplane = out + pbase;
    if (half == 0) dw_half<0, RESID>(plane, K, scl, shf, rplane, oplane, lane);
    else           dw_half<32, RESID>(plane, K, scl, shf, rplane, oplane, lane);
}

// ---------------------------------------------------------------------------
// K3: fused KAN + f2 + gate via bf16 MFMA, NCHW in-place.
// ROUND 4: closed-form uniform cubic B-spline basis (4 nonzero weights,
// dword-select placement into the 8-slot fragment) replaces Cox-de Boor;
// staging thread owns 8 CONSECUTIVE channels so silu/A2 rows pack as two
// b128 stores (no b16 scatters). Same fragment/XOR convention as round 3.
// ---------------------------------------------------------------------------
__global__ __launch_bounds__(256) void k_kan_mfma(
    float* __restrict__ xdio, const short* __restrict__ W1f,
    const short* __restrict__ W2f, const float* __restrict__ kb,
    const float* __restrict__ f2b)
{
    __shared__ __align__(16) short As1[2 * 18 * 64 * 8];  // 36 KB
    __shared__ __align__(16) short As2[2 * 2 * 64 * 8];   //  4 KB
    const int tid = threadIdx.x;
    const int tg0 = blockIdx.x * 32;
    const int bb = tg0 >> 12, pix0 = tg0 & 4095;
    float* xb = xdio + (size_t)bb * CD * PLANE + pix0;
    const int tkn = tid & 31;
    const int w5 = tid >> 5;
    const int mt = tkn >> 4, m = tkn & 15;

    short8v vpk, spk;
#pragma unroll
    for (int p = 0; p < 8; ++p) {
        const int c = w5 * 8 + p;
        const float v = xb[(size_t)c * PLANE + tkn];

        // silu + raw value, packed bf16 (static index)
        const float sl = v / (1.0f + __expf(-v));
        vpk[p] = f2bf(v);
        spk[p] = f2bf(sl);

        // closed-form uniform cubic B-spline: interval i0, frac u
        const float tt = (v + 2.2f) * 2.5f;
        const float fi = floorf(tt);
        const int i0 = (int)fi;
        const float u = tt - fi;
        const bool inr = (tt >= 0.0f) && (tt < 11.0f);
        const float u2 = u * u, u3 = u2 * u;
        const float w0 = (1.f / 6.f) * (1.f - 3.f * u + 3.f * u2 - u3);
        const float w1 = (1.f / 6.f) * (3.f * u3 - 6.f * u2 + 4.f);
        const float w2 = (1.f / 6.f) * (-3.f * u3 + 3.f * u2 + 3.f * u + 1.f);
        const float w3 = (1.f / 6.f) * u3;
        const unsigned int W01 = pk2bf(w0, w1);
        const unsigned int W23 = pk2bf(w2, w3);
        // window placement: q0 = i0-3 = 2a+b; contents per parity
        const int q0 = i0 - 3;
        int a = q0 >> 1;
        const int bpar = q0 & 1;
        if (!inr) a = 100;
        const unsigned int A0c = W01 << 16;
        const unsigned int A1c = (W01 >> 16) | (W23 << 16);
        const unsigned int A2c = W23 >> 16;
        const unsigned int C0 = bpar ? A0c : W01;
        const unsigned int C1 = bpar ? A1c : W23;
        const unsigned int C2 = bpar ? A2c : 0u;
        u32x4 D;
        D.x = (a == 0) ? C0 : (a == -1) ? C1 : (a == -2) ? C2 : 0u;
        D.y = (a == 1) ? C0 : (a == 0) ? C1 : (a == -1) ? C2 : 0u;
        D.z = (a == 2) ? C0 : (a == 1) ? C1 : (a == 0) ? C2 : 0u;
        D.w = (a == 3) ? C0 : (a == 2) ? C1 : (a == 1) ? C2 : 0u;

        const int s = c >> 2;                       // = w5*2 + (p>>2)
        const int phys = (((p & 3) << 4) | m) ^ (s & 7);
        *(u32x4*)&As1[((mt * 18 + s) * 64 + phys) * 8] = D;
    }
    {   // silu row block s2 and raw-v A2 block s3: one b128 each
        const int slot = ((w5 & 3) << 4) | m;
        const int s2 = 16 + (w5 >> 2);
        *(short8v*)&As1[((mt * 18 + s2) * 64 + (slot ^ (s2 & 7))) * 8] = spk;
        const int s3 = w5 >> 2;
        *(short8v*)&As2[((mt * 2 + s3) * 64 + (slot ^ (s3 & 7))) * 8] = vpk;
    }
    __syncthreads();

    const int cw = tid >> 6, l = tid & 63;
    f32x4 accA0 = {0.f,0.f,0.f,0.f}, accA1 = {0.f,0.f,0.f,0.f};
    f32x4 accB0 = {0.f,0.f,0.f,0.f}, accB1 = {0.f,0.f,0.f,0.f};
#pragma unroll 1
    for (int s = 0; s < 18; ++s) {
        const short8v bfr = *(const short8v*)&W1f[((s * 4 + cw) * 64 + l) * 8];
        const short8v a0 = *(const short8v*)&As1[((0 * 18 + s) * 64 + (l ^ (s & 7))) * 8];
        const short8v a1 = *(const short8v*)&As1[((1 * 18 + s) * 64 + (l ^ (s & 7))) * 8];
        accA0 = __builtin_amdgcn_mfma_f32_16x16x32_bf16(a0, bfr, accA0, 0, 0, 0);
        accA1 = __builtin_amdgcn_mfma_f32_16x16x32_bf16(a1, bfr, accA1, 0, 0, 0);
    }
#pragma unroll
    for (int s = 0; s < 2; ++s) {
        const short8v bfr = *(const short8v*)&W2f[((s * 4 + cw) * 64 + l) * 8];
        const short8v a0 = *(const short8v*)&As2[((0 * 2 + s) * 64 + (l ^ s)) * 8];
        const short8v a1 = *(const short8v*)&As2[((1 * 2 + s) * 64 + (l ^ s)) * 8];
        accB0 = __builtin_amdgcn_mfma_f32_16x16x32_bf16(a0, bfr, accB0, 0, 0, 0);
        accB1 = __builtin_amdgcn_mfma_f32_16x16x32_bf16(a1, bfr, accB1, 0, 0, 0);
    }
    __syncthreads();

    float* Osh = (float*)As1;
    const int j = (cw << 4) + (l & 15);
    const float kbj = kb[j], f2bj = f2b[j];
    const int rb = (l >> 4) << 2;
#pragma unroll
    for (int r = 0; r < 4; ++r) {
        Osh[j * 33 + rb + r]      = (accA0[r] + kbj) * (accB0[r] + f2bj);
        Osh[j * 33 + 16 + rb + r] = (accA1[r] + kbj) * (accB1[r] + f2bj);
    }
    __syncthreads();
#pragma unroll
    for (int q = 0; q < 8; ++q) {
        const int idx = tid + (q << 8);
        const int jj = idx >> 5, t2 = idx & 31;
        xb[(size_t)jj * PLANE + t2] = Osh[jj * 33 + t2];
    }
}

// ---------------------------------------------------------------------------
// K4: g 1x1 conv 64->64 + folded BN via MFMA. (unchanged from round 3)
// ---------------------------------------------------------------------------
__global__ __launch_bounds__(256) void k_gbn_mfma(
    const float* __restrict__ y, const short* __restrict__ WGf,
    const float* __restrict__ gs, const float* __restrict__ gsh,
    float* __restrict__ z)
{
    __shared__ __align__(16) char smem[34048];
    short* As = (short*)smem;
    float* Osh = (float*)smem;
    const int bid = blockIdx.x;
    const int b = bid >> 5, h0 = (bid & 31) * 2;
    const int tid = threadIdx.x;
    const float* yb = y + (size_t)b * CD * PLANE + h0 * WW;
#pragma unroll 1
    for (int p = 0; p < 32; ++p) {
        const int idx = tid + (p << 8);
        const int c = idx >> 7, rt = idx & 127;
        const float v = yb[(size_t)c * PLANE + rt];
        const int s = c >> 5, g = (c >> 3) & 3, e = c & 7;
        const int mt = rt >> 4, m = rt & 15;
        As[((mt * 2 + s) * 64 + (((g << 4) | m) ^ (s & 7))) * 8 + e] = f2bf(v);
    }
    __syncthreads();
    const int cw = tid >> 6, l = tid & 63;
    f32x4 acc[8];
#pragma unroll
    for (int i = 0; i < 8; ++i) acc[i] = (f32x4){0.f, 0.f, 0.f, 0.f};
#pragma unroll
    for (int s = 0; s < 2; ++s) {
        const short8v bfr = *(const short8v*)&WGf[((s * 4 + cw) * 64 + l) * 8];
        const int lx = l ^ (s & 7);
#pragma unroll
        for (int mt = 0; mt < 8; ++mt) {
            const short8v a = *(const short8v*)&As[((mt * 2 + s) * 64 + lx) * 8];
            acc[mt] = __builtin_amdgcn_mfma_f32_16x16x32_bf16(a, bfr, acc[mt], 0, 0, 0);
        }
    }
    __syncthreads();
    const int j = (cw << 4) + (l & 15);
    const float sj = gs[j], hj = gsh[j];
    const int rb = (l >> 4) << 2;
#pragma unroll
    for (int mt = 0; mt < 8; ++mt)
#pragma unroll
        for (int r = 0; r < 4; ++r)
            Osh[j * 133 + mt * 16 + rb + r] = acc[mt][r] * sj + hj;
    __syncthreads();
    float* zb = z + (size_t)b * CD * PLANE + h0 * WW;
#pragma unroll 1
    for (int p = 0; p < 32; ++p) {
        const int idx = tid + (p << 8);
        const int jj = idx >> 7, rt = idx & 127;
        zb[(size_t)jj * PLANE + rt] = Osh[jj * 133 + rt];
    }
}

// ---------------------------------------------------------------------------
extern "C" void kernel_launch(void* const* d_in, const int* in_sizes, int n_in,
                              void* d_out, int out_size, void* d_ws, size_t ws_size,
                              hipStream_t stream)
{
    (void)in_sizes; (void)n_in; (void)out_size; (void)ws_size;
    const float* x        = (const float*)d_in[0];
    const float* reduce_w = (const float*)d_in[1];
    const float* reduce_b = (const float*)d_in[2];
    const float* dw_w     = (const float*)d_in[3];
    const float* dw_b     = (const float*)d_in[4];
    const float* dw_g     = (const float*)d_in[5];
    const float* dw_beta  = (const float*)d_in[6];
    const float* dw_m     = (const float*)d_in[7];
    const float* dw_v     = (const float*)d_in[8];
    const float* f2_w     = (const float*)d_in[9];
    const float* f2_b     = (const float*)d_in[10];
    const float* coef     = (const float*)d_in[11];
    const float* sbase    = (const float*)d_in[12];
    const float* ssp      = (const float*)d_in[13];
    const float* kbias    = (const float*)d_in[14];
    const float* g_w      = (const float*)d_in[15];
    const float* g_b      = (const float*)d_in[16];
    const float* g_g      = (const float*)d_in[17];
    const float* g_beta   = (const float*)d_in[18];
    const float* g_m      = (const float*)d_in[19];
    const float* g_v      = (const float*)d_in[20];
    const float* dw2_w    = (const float*)d_in[21];
    const float* dw2_b    = (const float*)d_in[22];
    float* out = (float*)d_out;

    const size_t NEL = (size_t)BSZ * CD * PLANE;
    short* W1f = (short*)d_ws;
    short* W2f = W1f + 36864;
    short* WRf = W2f + 8192;
    short* WGf = WRf + 8192;
    float* cbuf = (float*)((char*)d_ws + 115200);
    float* inp = (float*)((char*)d_ws + 131072);
    float* xd  = inp + NEL;
    float* z   = xd + NEL;

    k_prep<<<225, 256, 0, stream>>>(coef, ssp, sbase, f2_w, reduce_w, g_w,
                                    dw_g, dw_beta, dw_m, dw_v, dw_b,
                                    g_g, g_beta, g_m, g_v, g_b,
                                    W1f, W2f, WRf, WGf, cbuf);
    k_reduce_mfma<<<BSZ * 32, 256, 0, stream>>>(x, WRf, reduce_b, inp);
    k_dwconv<false><<<BSZ * 16 * 2, 256, 0, stream>>>(inp, dw_w, cbuf, cbuf + 64, nullptr, xd);
    k_kan_mfma<<<NPIX / 32, 256, 0, stream>>>(xd, W1f, W2f, kbias, f2_b);
    k_gbn_mfma<<<BSZ * 32, 256, 0, stream>>>(xd, WGf, cbuf + 128, cbuf + 192, z);
    k_dwconv<true><<<BSZ * 16 * 2, 256, 0, stream>>>(z, dw2_w, nullptr, dw2_b, inp, out);
}

// Round 5
// 106.691 us; speedup vs baseline: 13.8289x; 1.1492x over previous
//
#include <hip/hip_runtime.h>
#include <hip/hip_bf16.h>

#define BSZ 32
#define CIN 128
#define CD 64
#define HH 64
#define WW 64
#define PLANE (HH * WW)
#define NPIX (BSZ * HH * WW)
#define NB 8
#define BN_EPS 1e-5f

typedef __attribute__((ext_vector_type(8))) short short8v;
typedef __attribute__((ext_vector_type(4))) float f32x4;
typedef __attribute__((ext_vector_type(4))) unsigned int u32x4;

static __device__ __forceinline__ short f2bf(float f) {
    __hip_bfloat16 h = __float2bfloat16(f);
    return __builtin_bit_cast(short, h);
}
// packed bf16 convert: dst.lo16 = bf16(lo), dst.hi16 = bf16(hi) (RNE)
static __device__ __forceinline__ unsigned int cvtpk(float lo, float hi) {
    unsigned int r;
    asm("v_cvt_pk_bf16_f32 %0, %1, %2" : "=v"(r) : "v"(lo), "v"(hi));
    return r;
}

// ---------------------------------------------------------------------------
// K0: prepack all matmul weights into MFMA B-fragment order (bf16) + fold BN.
// Fragment layout (verified round 2): element ((s*4+c)*64+l)*8+e holds
// W[k = s*32 + (l>>4)*8 + e][j = c*16 + (l&15)].
// ---------------------------------------------------------------------------
__global__ __launch_bounds__(256) void k_prep(
    const float* __restrict__ coef, const float* __restrict__ ssp,
    const float* __restrict__ sb, const float* __restrict__ f2w,
    const float* __restrict__ reduce_w, const float* __restrict__ g_w,
    const float* __restrict__ dw_g, const float* __restrict__ dw_beta,
    const float* __restrict__ dw_m, const float* __restrict__ dw_v,
    const float* __restrict__ dw_b, const float* __restrict__ g_g,
    const float* __restrict__ g_beta, const float* __restrict__ g_m,
    const float* __restrict__ g_v, const float* __restrict__ g_b,
    short* __restrict__ W1f, short* __restrict__ W2f,
    short* __restrict__ WRf, short* __restrict__ WGf,
    float* __restrict__ cbuf)
{
    const int idx = blockIdx.x * 256 + threadIdx.x;
    if (idx < 36864) {
        const int e = idx & 7, l = (idx >> 3) & 63, c = (idx >> 9) & 3, s = idx >> 11;
        const int k = s * 32 + ((l >> 4) << 3) + e;
        const int j = (c << 4) + (l & 15);
        float v;
        if (k < 512) {
            const int i = k >> 3, t = k & 7;
            v = coef[(i * 64 + j) * 8 + t] * ssp[i * 64 + j];
        } else {
            v = sb[(k - 512) * 64 + j];
        }
        W1f[idx] = f2bf(v);
    } else if (idx < 45056) {
        const int f = idx - 36864;
        const int e = f & 7, l = (f >> 3) & 63, c = (f >> 9) & 3, s = f >> 11;
        const int k = s * 32 + ((l >> 4) << 3) + e;
        const int j = (c << 4) + (l & 15);
        W2f[f] = f2bf(f2w[j * 64 + k]);
    } else if (idx < 53248) {
        const int f = idx - 45056;
        const int e = f & 7, l = (f >> 3) & 63, c = (f >> 9) & 3, s = f >> 11;
        const int k = s * 32 + ((l >> 4) << 3) + e;
        const int j = (c << 4) + (l & 15);
        WRf[f] = f2bf(reduce_w[j * CIN + k]);
    } else if (idx < 57344) {
        const int f = idx - 53248;
        const int e = f & 7, l = (f >> 3) & 63, c = (f >> 9) & 3, s = f >> 11;
        const int k = s * 32 + ((l >> 4) << 3) + e;
        const int j = (c << 4) + (l & 15);
        WGf[f] = f2bf(g_w[j * 64 + k]);
    } else if (idx < 57600) {
        const int q = (idx - 57344) >> 6, c = idx & 63;
        if (q == 0) cbuf[c] = dw_g[c] * rsqrtf(dw_v[c] + BN_EPS);
        else if (q == 1) {
            float sc = dw_g[c] * rsqrtf(dw_v[c] + BN_EPS);
            cbuf[64 + c] = (dw_b[c] - dw_m[c]) * sc + dw_beta[c];
        } else if (q == 2) cbuf[128 + c] = g_g[c] * rsqrtf(g_v[c] + BN_EPS);
        else {
            float sc = g_g[c] * rsqrtf(g_v[c] + BN_EPS);
            cbuf[192 + c] = (g_b[c] - g_m[c]) * sc + g_beta[c];
        }
    }
}

// ---------------------------------------------------------------------------
// K1: 1x1 conv 128->64 via MFMA. (unchanged from round 3)
// ---------------------------------------------------------------------------
__global__ __launch_bounds__(256) void k_reduce_mfma(
    const float* __restrict__ x, const short* __restrict__ WRf,
    const float* __restrict__ bias, float* __restrict__ out)
{
    __shared__ __align__(16) char smem[34048];
    short* As = (short*)smem;
    float* Osh = (float*)smem;
    const int bid = blockIdx.x;
    const int b = bid >> 5, h0 = (bid & 31) * 2;
    const int tid = threadIdx.x;
    const float* xb = x + (size_t)b * CIN * PLANE + h0 * WW;
#pragma unroll 1
    for (int p = 0; p < 64; ++p) {
        const int idx = tid + (p << 8);
        const int c = idx >> 7, rt = idx & 127;
        const float v = xb[(size_t)c * PLANE + rt];
        const int s = c >> 5, g = (c >> 3) & 3, e = c & 7;
        const int mt = rt >> 4, m = rt & 15;
        As[((mt * 4 + s) * 64 + (((g << 4) | m) ^ (s & 7))) * 8 + e] = f2bf(v);
    }
    __syncthreads();
    const int cw = tid >> 6, l = tid & 63;
    f32x4 acc[8];
#pragma unroll
    for (int i = 0; i < 8; ++i) acc[i] = (f32x4){0.f, 0.f, 0.f, 0.f};
#pragma unroll 1
    for (int s = 0; s < 4; ++s) {
        const short8v bfr = *(const short8v*)&WRf[((s * 4 + cw) * 64 + l) * 8];
        const int lx = l ^ (s & 7);
#pragma unroll
        for (int mt = 0; mt < 8; ++mt) {
            const short8v a = *(const short8v*)&As[((mt * 4 + s) * 64 + lx) * 8];
            acc[mt] = __builtin_amdgcn_mfma_f32_16x16x32_bf16(a, bfr, acc[mt], 0, 0, 0);
        }
    }
    __syncthreads();
    const int j = (cw << 4) + (l & 15);
    const float bj = bias[j];
    const int rb = (l >> 4) << 2;
#pragma unroll
    for (int mt = 0; mt < 8; ++mt)
#pragma unroll
        for (int r = 0; r < 4; ++r)
            Osh[j * 133 + mt * 16 + rb + r] = acc[mt][r] + bj;
    __syncthreads();
    float* ob = out + (size_t)b * CD * PLANE + h0 * WW;
#pragma unroll 1
    for (int p = 0; p < 32; ++p) {
        const int idx = tid + (p << 8);
        const int jj = idx >> 7, rt = idx & 127;
        ob[(size_t)jj * PLANE + rt] = Osh[jj * 133 + rt];
    }
}

// ---------------------------------------------------------------------------
// K2/K5: 7x7 depthwise conv, register-streaming. (unchanged from round 3)
// ---------------------------------------------------------------------------
template<int H0, bool RESID>
__device__ __forceinline__ void dw_half(
    const float* __restrict__ plane, const float (&K)[49],
    float scl, float shf, const float* __restrict__ rplane,
    float* __restrict__ oplane, int lane)
{
    float acc[7] = {0.f, 0.f, 0.f, 0.f, 0.f, 0.f, 0.f};
#pragma unroll
    for (int r = 0; r < 38; ++r) {
        const int ra = H0 + r - 3;
        float rowv = 0.f;
        if (ra >= 0 && ra < 64) rowv = plane[ra * 64 + lane];
        float sh[7];
        sh[3] = rowv;
#pragma unroll
        for (int d = 1; d <= 3; ++d) {
            float tp = __shfl(rowv, lane + d);
            sh[3 + d] = (lane + d < 64) ? tp : 0.f;
            float tm = __shfl(rowv, lane - d);
            sh[3 - d] = (lane - d >= 0) ? tm : 0.f;
        }
#pragma unroll
        for (int dy = 0; dy < 7; ++dy) {
            const int h = ra + 3 - dy;
            if (h >= H0 && h < H0 + 32 && h < 64) {
                const int slot = (h - H0) % 7;
#pragma unroll
                for (int dx = 0; dx < 7; ++dx)
                    acc[slot] = fmaf(sh[dx], K[dy * 7 + dx], acc[slot]);
            }
        }
        const int hd = ra - 3;
        if (hd >= H0 && hd < H0 + 32) {
            const int slot = (hd - H0) % 7;
            float val;
            if (RESID) val = acc[slot] + shf + rplane[hd * 64 + lane];
            else       val = acc[slot] * scl + shf;
            oplane[hd * 64 + lane] = val;
            acc[slot] = 0.f;
        }
    }
}

template<bool RESID>
__global__ __launch_bounds__(256) void k_dwconv(
    const float* __restrict__ in, const float* __restrict__ filt,
    const float* __restrict__ sc, const float* __restrict__ shv,
    const float* __restrict__ resid, float* __restrict__ out)
{
    const int bid = blockIdx.x;
    const int b = bid >> 5, c4 = (bid >> 1) & 15, half = bid & 1;
    const int c = c4 * 4 + (threadIdx.x >> 6);
    const int lane = threadIdx.x & 63;
    const size_t pbase = ((size_t)b * CD + c) * PLANE;
    const float* plane = in + pbase;
    const float* wp = filt + c * 49;
    float K[49];
#pragma unroll
    for (int q = 0; q < 49; ++q) K[q] = wp[q];
    const float scl = RESID ? 1.f : sc[c];
    const float shf = shv[c];
    const float* rplane = RESID ? (resid + pbase) : nullptr;
    float* oplane = out + pbase;
    if (half == 0) dw_half<0, RESID>(plane, K, scl, shf, rplane, oplane, lane);
    else           dw_half<32, RESID>(plane, K, scl, shf, rplane, oplane, lane);
}

// ---------------------------------------------------------------------------
// K3: fused KAN + f2 + gate + g-conv + BN via bf16 MFMA, NCHW -> NCHW.
// ROUND 5: (a) window placement by zero-fill + 3 clamped ds_write_b32
// (OOB stores write 0 to a provably-empty dword d&3 of the own row);
// (b) v_cvt_pk_bf16_f32 paired converts; (c) g 1x1 conv + BN fused: y is
// scattered as bf16 A-frags into the As2 region (after GEMM2 is done),
// 4 more MFMAs with WGf, BN-folded epilogue writes z directly.
// ---------------------------------------------------------------------------
__global__ __launch_bounds__(256) void k_kan_fused(
    const float* __restrict__ xd, const short* __restrict__ W1f,
    const short* __restrict__ W2f, const short* __restrict__ WGf,
    const float* __restrict__ kb, const float* __restrict__ f2b,
    const float* __restrict__ gs, const float* __restrict__ gsh,
    float* __restrict__ z)
{
    __shared__ __align__(16) short As1[2 * 18 * 64 * 8];  // 36 KB
    __shared__ __align__(16) short As2[2 * 2 * 64 * 8];   //  4 KB (v-frags -> y-frags)
    const int tid = threadIdx.x;
    const int tg0 = blockIdx.x * 32;
    const int bb = tg0 >> 12, pix0 = tg0 & 4095;
    const float* xb = xd + (size_t)bb * CD * PLANE + pix0;
    const int tkn = tid & 31;
    const int w5 = tid >> 5;
    const int mt = tkn >> 4, m = tkn & 15;

    float vf[8], sf[8];
#pragma unroll
    for (int p = 0; p < 8; ++p) {
        const int c = w5 * 8 + p;
        const float v = xb[(size_t)c * PLANE + tkn];
        vf[p] = v;
        sf[p] = v * __builtin_amdgcn_rcpf(1.0f + __expf(-v));

        // closed-form uniform cubic B-spline: interval i0, frac u
        const float tt = (v + 2.2f) * 2.5f;
        const float fi = floorf(tt);
        const int i0 = (int)fi;
        const float u = tt - fi;
        const bool inr = (tt >= 0.0f) && (tt < 11.0f);
        const float u2 = u * u, u3 = u2 * u;
        const float t1 = 1.f - u;
        const float w0 = (1.f / 6.f) * t1 * t1 * t1;
        const float w3 = (1.f / 6.f) * u3;
        const float w1 = fmaf(0.5f, u3, 2.f / 3.f) - u2;
        const float w2 = 1.f - w0 - w1 - w3;
        const unsigned W01 = cvtpk(w0, w1);
        const unsigned W23 = cvtpk(w2, w3);
        const int q0 = i0 - 3;
        int a = q0 >> 1;
        const int bpar = q0 & 1;
        if (!inr) a = -100;
        const unsigned A1c = (W01 >> 16) | (W23 << 16);
        const unsigned C0 = bpar ? (W01 << 16) : W01;
        const unsigned C1 = bpar ? A1c : W23;
        const unsigned C2 = bpar ? (W23 >> 16) : 0u;

        const int s = w5 * 2 + (p >> 2);
        const int phys = (((p & 3) << 4) | m) ^ (s & 7);
        unsigned* row = (unsigned*)&As1[((mt * 18 + s) * 64 + phys) * 8];
        *(u32x4*)row = (u32x4){0u, 0u, 0u, 0u};
        // 3 clamped scatter stores; OOB -> content 0 into an empty dword
        int d = a;
        row[d & 3] = ((unsigned)d <= 3u) ? C0 : 0u;
        d = a + 1;
        row[d & 3] = ((unsigned)d <= 3u) ? C1 : 0u;
        d = a + 2;
        row[d & 3] = ((unsigned)d <= 3u) ? C2 : 0u;
    }
    {   // silu + raw-v fragments: paired converts, one b128 store each
        short8v vpk, spk;
#pragma unroll
        for (int q = 0; q < 4; ++q) {
            ((unsigned*)&vpk)[q] = cvtpk(vf[2 * q], vf[2 * q + 1]);
            ((unsigned*)&spk)[q] = cvtpk(sf[2 * q], sf[2 * q + 1]);
        }
        const int slot = ((w5 & 3) << 4) | m;
        const int s2 = 16 + (w5 >> 2);
        *(short8v*)&As1[((mt * 18 + s2) * 64 + (slot ^ (s2 & 7))) * 8] = spk;
        const int s3 = w5 >> 2;
        *(short8v*)&As2[((mt * 2 + s3) * 64 + (slot ^ (s3 & 7))) * 8] = vpk;
    }
    __syncthreads();

    const int cw = tid >> 6, l = tid & 63;
    f32x4 accA0 = {0.f,0.f,0.f,0.f}, accA1 = {0.f,0.f,0.f,0.f};
    f32x4 accB0 = {0.f,0.f,0.f,0.f}, accB1 = {0.f,0.f,0.f,0.f};
#pragma unroll 1
    for (int s = 0; s < 18; ++s) {
        const short8v bfr = *(const short8v*)&W1f[((s * 4 + cw) * 64 + l) * 8];
        const short8v a0 = *(const short8v*)&As1[((0 * 18 + s) * 64 + (l ^ (s & 7))) * 8];
        const short8v a1 = *(const short8v*)&As1[((1 * 18 + s) * 64 + (l ^ (s & 7))) * 8];
        accA0 = __builtin_amdgcn_mfma_f32_16x16x32_bf16(a0, bfr, accA0, 0, 0, 0);
        accA1 = __builtin_amdgcn_mfma_f32_16x16x32_bf16(a1, bfr, accA1, 0, 0, 0);
    }
#pragma unroll
    for (int s = 0; s < 2; ++s) {
        const short8v bfr = *(const short8v*)&W2f[((s * 4 + cw) * 64 + l) * 8];
        const short8v a0 = *(const short8v*)&As2[((0 * 2 + s) * 64 + (l ^ s)) * 8];
        const short8v a1 = *(const short8v*)&As2[((1 * 2 + s) * 64 + (l ^ s)) * 8];
        accB0 = __builtin_amdgcn_mfma_f32_16x16x32_bf16(a0, bfr, accB0, 0, 0, 0);
        accB1 = __builtin_amdgcn_mfma_f32_16x16x32_bf16(a1, bfr, accB1, 0, 0, 0);
    }

    // y = (x1+kb)*(x2+f2b) in regs
    const int j = (cw << 4) + (l & 15);
    const float kbj = kb[j], f2bj = f2b[j];
    const int rb = (l >> 4) << 2;
    float y0[4], y1[4];
#pragma unroll
    for (int r = 0; r < 4; ++r) {
        y0[r] = (accA0[r] + kbj) * (accB0[r] + f2bj);
        y1[r] = (accA1[r] + kbj) * (accB1[r] + f2bj);
    }
    __syncthreads();   // all waves done reading As2 (GEMM2)

    // scatter y -> As2 region as bf16 A-frags for the g-conv GEMM
    const int s_ = j >> 5, g_ = (j >> 3) & 3, e_ = j & 7;
#pragma unroll
    for (int r = 0; r < 4; ++r) {
        const int m0 = rb + r;
        const int ph = ((g_ << 4) | m0) ^ s_;
        const unsigned pk = cvtpk(y0[r], y1[r]);
        As2[((0 * 2 + s_) * 64 + ph) * 8 + e_] = (short)pk;
        As2[((1 * 2 + s_) * 64 + ph) * 8 + e_] = (short)(pk >> 16);
    }
    __syncthreads();

    // GEMM3: z = y @ g_w^T (BN folded in epilogue)
    f32x4 acc30 = {0.f,0.f,0.f,0.f}, acc31 = {0.f,0.f,0.f,0.f};
#pragma unroll
    for (int s = 0; s < 2; ++s) {
        const short8v bfr = *(const short8v*)&WGf[((s * 4 + cw) * 64 + l) * 8];
        const short8v a0 = *(const short8v*)&As2[((0 * 2 + s) * 64 + (l ^ s)) * 8];
        const short8v a1 = *(const short8v*)&As2[((1 * 2 + s) * 64 + (l ^ s)) * 8];
        acc30 = __builtin_amdgcn_mfma_f32_16x16x32_bf16(a0, bfr, acc30, 0, 0, 0);
        acc31 = __builtin_amdgcn_mfma_f32_16x16x32_bf16(a1, bfr, acc31, 0, 0, 0);
    }

    float* Osh = (float*)As1;   // safe: all waves are past GEMM1's As1 reads
    const float sj = gs[j], hj = gsh[j];
#pragma unroll
    for (int r = 0; r < 4; ++r) {
        Osh[j * 33 + rb + r]      = acc30[r] * sj + hj;
        Osh[j * 33 + 16 + rb + r] = acc31[r] * sj + hj;
    }
    __syncthreads();
    float* zb = z + (size_t)bb * CD * PLANE + pix0;
#pragma unroll
    for (int q = 0; q < 8; ++q) {
        const int idx = tid + (q << 8);
        const int jj = idx >> 5, t2 = idx & 31;
        zb[(size_t)jj * PLANE + t2] = Osh[jj * 33 + t2];
    }
}

// ---------------------------------------------------------------------------
extern "C" void kernel_launch(void* const* d_in, const int* in_sizes, int n_in,
                              void* d_out, int out_size, void* d_ws, size_t ws_size,
                              hipStream_t stream)
{
    (void)in_sizes; (void)n_in; (void)out_size; (void)ws_size;
    const float* x        = (const float*)d_in[0];
    const float* reduce_w = (const float*)d_in[1];
    const float* reduce_b = (const float*)d_in[2];
    const float* dw_w     = (const float*)d_in[3];
    const float* dw_b     = (const float*)d_in[4];
    const float* dw_g     = (const float*)d_in[5];
    const float* dw_beta  = (const float*)d_in[6];
    const float* dw_m     = (const float*)d_in[7];
    const float* dw_v     = (const float*)d_in[8];
    const float* f2_w     = (const float*)d_in[9];
    const float* f2_b     = (const float*)d_in[10];
    const float* coef     = (const float*)d_in[11];
    const float* sbase    = (const float*)d_in[12];
    const float* ssp      = (const float*)d_in[13];
    const float* kbias    = (const float*)d_in[14];
    const float* g_w      = (const float*)d_in[15];
    const float* g_b      = (const float*)d_in[16];
    const float* g_g      = (const float*)d_in[17];
    const float* g_beta   = (const float*)d_in[18];
    const float* g_m      = (const float*)d_in[19];
    const float* g_v      = (const float*)d_in[20];
    const float* dw2_w    = (const float*)d_in[21];
    const float* dw2_b    = (const float*)d_in[22];
    float* out = (float*)d_out;

    const size_t NEL = (size_t)BSZ * CD * PLANE;
    short* W1f = (short*)d_ws;
    short* W2f = W1f + 36864;
    short* WRf = W2f + 8192;
    short* WGf = WRf + 8192;
    float* cbuf = (float*)((char*)d_ws + 115200);
    float* inp = (float*)((char*)d_ws + 131072);
    float* xdb = inp + NEL;
    float* z   = xdb + NEL;

    k_prep<<<225, 256, 0, stream>>>(coef, ssp, sbase, f2_w, reduce_w, g_w,
                                    dw_g, dw_beta, dw_m, dw_v, dw_b,
                                    g_g, g_beta, g_m, g_v, g_b,
                                    W1f, W2f, WRf, WGf, cbuf);
    k_reduce_mfma<<<BSZ * 32, 256, 0, stream>>>(x, WRf, reduce_b, inp);
    k_dwconv<false><<<BSZ * 16 * 2, 256, 0, stream>>>(inp, dw_w, cbuf, cbuf + 64, nullptr, xdb);
    k_kan_fused<<<NPIX / 32, 256, 0, stream>>>(xdb, W1f, W2f, WGf, kbias, f2_b,
                                               cbuf + 128, cbuf + 192, z);
    k_dwconv<true><<<BSZ * 16 * 2, 256, 0, stream>>>(z, dw2_w, nullptr, dw2_b, inp, out);
}

// Round 6
// 105.805 us; speedup vs baseline: 13.9448x; 1.0084x over previous
//
#include <hip/hip_runtime.h>
#include <hip/hip_bf16.h>

#define BSZ 32
#define CIN 128
#define CD 64
#define HH 64
#define WW 64
#define PLANE (HH * WW)
#define NPIX (BSZ * HH * WW)
#define NB 8
#define BN_EPS 1e-5f

typedef __attribute__((ext_vector_type(8))) short short8v;
typedef __attribute__((ext_vector_type(4))) float f32x4;
typedef __attribute__((ext_vector_type(4))) unsigned int u32x4;

static __device__ __forceinline__ short f2bf(float f) {
    __hip_bfloat16 h = __float2bfloat16(f);
    return __builtin_bit_cast(short, h);
}
// packed bf16 convert: dst.lo16 = bf16(lo), dst.hi16 = bf16(hi) (RNE)
static __device__ __forceinline__ unsigned int cvtpk(float lo, float hi) {
    unsigned int r;
    asm("v_cvt_pk_bf16_f32 %0, %1, %2" : "=v"(r) : "v"(lo), "v"(hi));
    return r;
}

// ---------------------------------------------------------------------------
// K0: prepack all matmul weights into MFMA B-fragment order (bf16) + fold BN.
// Fragment layout (verified round 2): element ((s*4+c)*64+l)*8+e holds
// W[k = s*32 + (l>>4)*8 + e][j = c*16 + (l&15)].
// ---------------------------------------------------------------------------
__global__ __launch_bounds__(256) void k_prep(
    const float* __restrict__ coef, const float* __restrict__ ssp,
    const float* __restrict__ sb, const float* __restrict__ f2w,
    const float* __restrict__ reduce_w, const float* __restrict__ g_w,
    const float* __restrict__ dw_g, const float* __restrict__ dw_beta,
    const float* __restrict__ dw_m, const float* __restrict__ dw_v,
    const float* __restrict__ dw_b, const float* __restrict__ g_g,
    const float* __restrict__ g_beta, const float* __restrict__ g_m,
    const float* __restrict__ g_v, const float* __restrict__ g_b,
    short* __restrict__ W1f, short* __restrict__ W2f,
    short* __restrict__ WRf, short* __restrict__ WGf,
    float* __restrict__ cbuf)
{
    const int idx = blockIdx.x * 256 + threadIdx.x;
    if (idx < 36864) {
        const int e = idx & 7, l = (idx >> 3) & 63, c = (idx >> 9) & 3, s = idx >> 11;
        const int k = s * 32 + ((l >> 4) << 3) + e;
        const int j = (c << 4) + (l & 15);
        float v;
        if (k < 512) {
            const int i = k >> 3, t = k & 7;
            v = coef[(i * 64 + j) * 8 + t] * ssp[i * 64 + j];
        } else {
            v = sb[(k - 512) * 64 + j];
        }
        W1f[idx] = f2bf(v);
    } else if (idx < 45056) {
        const int f = idx - 36864;
        const int e = f & 7, l = (f >> 3) & 63, c = (f >> 9) & 3, s = f >> 11;
        const int k = s * 32 + ((l >> 4) << 3) + e;
        const int j = (c << 4) + (l & 15);
        W2f[f] = f2bf(f2w[j * 64 + k]);
    } else if (idx < 53248) {
        const int f = idx - 45056;
        const int e = f & 7, l = (f >> 3) & 63, c = (f >> 9) & 3, s = f >> 11;
        const int k = s * 32 + ((l >> 4) << 3) + e;
        const int j = (c << 4) + (l & 15);
        WRf[f] = f2bf(reduce_w[j * CIN + k]);
    } else if (idx < 57344) {
        const int f = idx - 53248;
        const int e = f & 7, l = (f >> 3) & 63, c = (f >> 9) & 3, s = f >> 11;
        const int k = s * 32 + ((l >> 4) << 3) + e;
        const int j = (c << 4) + (l & 15);
        WGf[f] = f2bf(g_w[j * 64 + k]);
    } else if (idx < 57600) {
        const int q = (idx - 57344) >> 6, c = idx & 63;
        if (q == 0) cbuf[c] = dw_g[c] * rsqrtf(dw_v[c] + BN_EPS);
        else if (q == 1) {
            float sc = dw_g[c] * rsqrtf(dw_v[c] + BN_EPS);
            cbuf[64 + c] = (dw_b[c] - dw_m[c]) * sc + dw_beta[c];
        } else if (q == 2) cbuf[128 + c] = g_g[c] * rsqrtf(g_v[c] + BN_EPS);
        else {
            float sc = g_g[c] * rsqrtf(g_v[c] + BN_EPS);
            cbuf[192 + c] = (g_b[c] - g_m[c]) * sc + g_beta[c];
        }
    }
}

// ---------------------------------------------------------------------------
// K1: 1x1 conv 128->64 via MFMA. (unchanged from round 3)
// ---------------------------------------------------------------------------
__global__ __launch_bounds__(256) void k_reduce_mfma(
    const float* __restrict__ x, const short* __restrict__ WRf,
    const float* __restrict__ bias, float* __restrict__ out)
{
    __shared__ __align__(16) char smem[34048];
    short* As = (short*)smem;
    float* Osh = (float*)smem;
    const int bid = blockIdx.x;
    const int b = bid >> 5, h0 = (bid & 31) * 2;
    const int tid = threadIdx.x;
    const float* xb = x + (size_t)b * CIN * PLANE + h0 * WW;
#pragma unroll 1
    for (int p = 0; p < 64; ++p) {
        const int idx = tid + (p << 8);
        const int c = idx >> 7, rt = idx & 127;
        const float v = xb[(size_t)c * PLANE + rt];
        const int s = c >> 5, g = (c >> 3) & 3, e = c & 7;
        const int mt = rt >> 4, m = rt & 15;
        As[((mt * 4 + s) * 64 + (((g << 4) | m) ^ (s & 7))) * 8 + e] = f2bf(v);
    }
    __syncthreads();
    const int cw = tid >> 6, l = tid & 63;
    f32x4 acc[8];
#pragma unroll
    for (int i = 0; i < 8; ++i) acc[i] = (f32x4){0.f, 0.f, 0.f, 0.f};
#pragma unroll 1
    for (int s = 0; s < 4; ++s) {
        const short8v bfr = *(const short8v*)&WRf[((s * 4 + cw) * 64 + l) * 8];
        const int lx = l ^ (s & 7);
#pragma unroll
        for (int mt = 0; mt < 8; ++mt) {
            const short8v a = *(const short8v*)&As[((mt * 4 + s) * 64 + lx) * 8];
            acc[mt] = __builtin_amdgcn_mfma_f32_16x16x32_bf16(a, bfr, acc[mt], 0, 0, 0);
        }
    }
    __syncthreads();
    const int j = (cw << 4) + (l & 15);
    const float bj = bias[j];
    const int rb = (l >> 4) << 2;
#pragma unroll
    for (int mt = 0; mt < 8; ++mt)
#pragma unroll
        for (int r = 0; r < 4; ++r)
            Osh[j * 133 + mt * 16 + rb + r] = acc[mt][r] + bj;
    __syncthreads();
    float* ob = out + (size_t)b * CD * PLANE + h0 * WW;
#pragma unroll 1
    for (int p = 0; p < 32; ++p) {
        const int idx = tid + (p << 8);
        const int jj = idx >> 7, rt = idx & 127;
        ob[(size_t)jj * PLANE + rt] = Osh[jj * 133 + rt];
    }
}

// ---------------------------------------------------------------------------
// K2/K5: 7x7 depthwise conv, register-streaming.
// ROUND 6: quarter-plane strips (16 output rows/wave, 22 input rows) ->
// 2048 blocks = 8 blocks/CU = 100% static occupancy (was 50%, measured 36%
// with VALU 26% / HBM 19% => latency-bound, needs more waves). Strip-
// relative row indices stay compile-time so the loop stays fully unrolled.
// ---------------------------------------------------------------------------
template<bool RESID>
__global__ __launch_bounds__(256) void k_dwconv(
    const float* __restrict__ in, const float* __restrict__ filt,
    const float* __restrict__ sc, const float* __restrict__ shv,
    const float* __restrict__ resid, float* __restrict__ out)
{
    const int bid = blockIdx.x;
    const int b = bid >> 6, c4 = (bid >> 2) & 15, strip = bid & 3;
    const int H0 = strip << 4;
    const int c = c4 * 4 + (threadIdx.x >> 6);
    const int lane = threadIdx.x & 63;
    const size_t pbase = ((size_t)b * CD + c) * PLANE;
    const float* plane = in + pbase;
    const float* wp = filt + c * 49;
    float K[49];
#pragma unroll
    for (int q = 0; q < 49; ++q) K[q] = wp[q];
    const float scl = RESID ? 1.f : sc[c];
    const float shf = shv[c];
    const float* rplane = RESID ? (resid + pbase) : nullptr;
    float* oplane = out + pbase;

    float acc[7] = {0.f, 0.f, 0.f, 0.f, 0.f, 0.f, 0.f};
#pragma unroll
    for (int rr = 0; rr < 22; ++rr) {
        const int ra = H0 + rr - 3;           // input row (uniform)
        float rowv = 0.f;
        if (ra >= 0 && ra < 64) rowv = plane[ra * 64 + lane];
        float sh[7];
        sh[3] = rowv;
#pragma unroll
        for (int d = 1; d <= 3; ++d) {
            float tp = __shfl(rowv, lane + d);
            sh[3 + d] = (lane + d < 64) ? tp : 0.f;
            float tm = __shfl(rowv, lane - d);
            sh[3 - d] = (lane - d >= 0) ? tm : 0.f;
        }
#pragma unroll
        for (int dy = 0; dy < 7; ++dy) {
            const int o = rr - dy;            // strip-relative output row (CT)
            if (o >= 0 && o < 16) {
                const int slot = o % 7;
#pragma unroll
                for (int dx = 0; dx < 7; ++dx)
                    acc[slot] = fmaf(sh[dx], K[dy * 7 + dx], acc[slot]);
            }
        }
        const int done = rr - 6;              // completed output row (CT)
        if (done >= 0 && done < 16) {
            const int slot = done % 7;
            const int h = H0 + done;
            float val;
            if (RESID) val = acc[slot] + shf + rplane[h * 64 + lane];
            else       val = acc[slot] * scl + shf;
            oplane[h * 64 + lane] = val;
            acc[slot] = 0.f;
        }
    }
}

// ---------------------------------------------------------------------------
// K3: fused KAN + f2 + gate + g-conv + BN via bf16 MFMA, NCHW -> NCHW.
// ROUND 6: spline window placement back to cndmask-select + b128 store
// (round-4 pattern, measured 262K conflicts vs 2.2M for the b32 scatter);
// GEMM3 A-staging via conflict-free f32 roundtrip: y -> padded Ysh (b32,
// stride 33) -> barrier -> coalesced re-read 8ch/thread -> cvtpk -> one
// b128 fragment store (the verified staging pattern).
// ---------------------------------------------------------------------------
__global__ __launch_bounds__(256) void k_kan_fused(
    const float* __restrict__ xd, const short* __restrict__ W1f,
    const short* __restrict__ W2f, const short* __restrict__ WGf,
    const float* __restrict__ kb, const float* __restrict__ f2b,
    const float* __restrict__ gs, const float* __restrict__ gsh,
    float* __restrict__ z)
{
    __shared__ __align__(16) short As1[2 * 18 * 64 * 8];  // 36 KB (aliased as Ysh/Osh)
    __shared__ __align__(16) short As2[2 * 2 * 64 * 8];   //  4 KB (v-frags -> y-frags)
    const int tid = threadIdx.x;
    const int tg0 = blockIdx.x * 32;
    const int bb = tg0 >> 12, pix0 = tg0 & 4095;
    const float* xb = xd + (size_t)bb * CD * PLANE + pix0;
    const int tkn = tid & 31;
    const int w5 = tid >> 5;
    const int mt = tkn >> 4, m = tkn & 15;

    float vf[8], sf[8];
#pragma unroll
    for (int p = 0; p < 8; ++p) {
        const int c = w5 * 8 + p;
        const float v = xb[(size_t)c * PLANE + tkn];
        vf[p] = v;
        sf[p] = v * __builtin_amdgcn_rcpf(1.0f + __expf(-v));

        // closed-form uniform cubic B-spline: interval i0, frac u
        const float tt = (v + 2.2f) * 2.5f;
        const float fi = floorf(tt);
        const int i0 = (int)fi;
        const float u = tt - fi;
        const bool inr = (tt >= 0.0f) && (tt < 11.0f);
        const float u2 = u * u, u3 = u2 * u;
        const float t1 = 1.f - u;
        const float w0 = (1.f / 6.f) * t1 * t1 * t1;
        const float w3 = (1.f / 6.f) * u3;
        const float w1 = fmaf(0.5f, u3, 2.f / 3.f) - u2;
        const float w2 = 1.f - w0 - w1 - w3;
        const unsigned W01 = cvtpk(w0, w1);
        const unsigned W23 = cvtpk(w2, w3);
        // window placement via dword select (conflict-free b128 store)
        const int q0 = i0 - 3;
        int a = q0 >> 1;
        const int bpar = q0 & 1;
        if (!inr) a = 100;
        const unsigned A1c = (W01 >> 16) | (W23 << 16);
        const unsigned C0 = bpar ? (W01 << 16) : W01;
        const unsigned C1 = bpar ? A1c : W23;
        const unsigned C2 = bpar ? (W23 >> 16) : 0u;
        u32x4 D;
        D.x = (a == 0) ? C0 : (a == -1) ? C1 : (a == -2) ? C2 : 0u;
        D.y = (a == 1) ? C0 : (a == 0) ? C1 : (a == -1) ? C2 : 0u;
        D.z = (a == 2) ? C0 : (a == 1) ? C1 : (a == 0) ? C2 : 0u;
        D.w = (a == 3) ? C0 : (a == 2) ? C1 : (a == 1) ? C2 : 0u;

        const int s = w5 * 2 + (p >> 2);
        const int phys = (((p & 3) << 4) | m) ^ (s & 7);
        *(u32x4*)&As1[((mt * 18 + s) * 64 + phys) * 8] = D;
    }
    {   // silu + raw-v fragments: paired converts, one b128 store each
        short8v vpk, spk;
#pragma unroll
        for (int q = 0; q < 4; ++q) {
            ((unsigned*)&vpk)[q] = cvtpk(vf[2 * q], vf[2 * q + 1]);
            ((unsigned*)&spk)[q] = cvtpk(sf[2 * q], sf[2 * q + 1]);
        }
        const int slot = ((w5 & 3) << 4) | m;
        const int s2 = 16 + (w5 >> 2);
        *(short8v*)&As1[((mt * 18 + s2) * 64 + (slot ^ (s2 & 7))) * 8] = spk;
        const int s3 = w5 >> 2;
        *(short8v*)&As2[((mt * 2 + s3) * 64 + (slot ^ (s3 & 7))) * 8] = vpk;
    }
    __syncthreads();   // B1: staging complete

    const int cw = tid >> 6, l = tid & 63;
    f32x4 accA0 = {0.f,0.f,0.f,0.f}, accA1 = {0.f,0.f,0.f,0.f};
    f32x4 accB0 = {0.f,0.f,0.f,0.f}, accB1 = {0.f,0.f,0.f,0.f};
#pragma unroll 1
    for (int s = 0; s < 18; ++s) {
        const short8v bfr = *(const short8v*)&W1f[((s * 4 + cw) * 64 + l) * 8];
        const short8v a0 = *(const short8v*)&As1[((0 * 18 + s) * 64 + (l ^ (s & 7))) * 8];
        const short8v a1 = *(const short8v*)&As1[((1 * 18 + s) * 64 + (l ^ (s & 7))) * 8];
        accA0 = __builtin_amdgcn_mfma_f32_16x16x32_bf16(a0, bfr, accA0, 0, 0, 0);
        accA1 = __builtin_amdgcn_mfma_f32_16x16x32_bf16(a1, bfr, accA1, 0, 0, 0);
    }
#pragma unroll
    for (int s = 0; s < 2; ++s) {
        const short8v bfr = *(const short8v*)&W2f[((s * 4 + cw) * 64 + l) * 8];
        const short8v a0 = *(const short8v*)&As2[((0 * 2 + s) * 64 + (l ^ s)) * 8];
        const short8v a1 = *(const short8v*)&As2[((1 * 2 + s) * 64 + (l ^ s)) * 8];
        accB0 = __builtin_amdgcn_mfma_f32_16x16x32_bf16(a0, bfr, accB0, 0, 0, 0);
        accB1 = __builtin_amdgcn_mfma_f32_16x16x32_bf16(a1, bfr, accB1, 0, 0, 0);
    }

    // y = (x1+kb)*(x2+f2b) in regs
    const int j = (cw << 4) + (l & 15);
    const float kbj = kb[j], f2bj = f2b[j];
    const int rb = (l >> 4) << 2;
    float y0[4], y1[4];
#pragma unroll
    for (int r = 0; r < 4; ++r) {
        y0[r] = (accA0[r] + kbj) * (accB0[r] + f2bj);
        y1[r] = (accA1[r] + kbj) * (accB1[r] + f2bj);
    }
    __syncthreads();   // B2: all As1/As2 reads done

    // y -> padded f32 Ysh (reuses As1 region); stride 33 => near-conflict-free
    float* Ysh = (float*)As1;
#pragma unroll
    for (int r = 0; r < 4; ++r) {
        Ysh[j * 33 + rb + r]      = y0[r];
        Ysh[j * 33 + 16 + rb + r] = y1[r];
    }
    __syncthreads();   // B3: Ysh complete

    // re-stage y as bf16 A-frags into As2 (coalesced reads + b128 store)
    {
        float yv[8];
#pragma unroll
        for (int p = 0; p < 8; ++p) yv[p] = Ysh[(w5 * 8 + p) * 33 + tkn];
        short8v ypk;
#pragma unroll
        for (int q = 0; q < 4; ++q)
            ((unsigned*)&ypk)[q] = cvtpk(yv[2 * q], yv[2 * q + 1]);
        const int slot = ((w5 & 3) << 4) | m;
        const int s3 = w5 >> 2;
        *(short8v*)&As2[((mt * 2 + s3) * 64 + (slot ^ (s3 & 7))) * 8] = ypk;
    }
    __syncthreads();   // B4: y-frags complete

    // GEMM3: z = y @ g_w^T (BN folded in epilogue)
    f32x4 acc30 = {0.f,0.f,0.f,0.f}, acc31 = {0.f,0.f,0.f,0.f};
#pragma unroll
    for (int s = 0; s < 2; ++s) {
        const short8v bfr = *(const short8v*)&WGf[((s * 4 + cw) * 64 + l) * 8];
        const short8v a0 = *(const short8v*)&As2[((0 * 2 + s) * 64 + (l ^ s)) * 8];
        const short8v a1 = *(const short8v*)&As2[((1 * 2 + s) * 64 + (l ^ s)) * 8];
        acc30 = __builtin_amdgcn_mfma_f32_16x16x32_bf16(a0, bfr, acc30, 0, 0, 0);
        acc31 = __builtin_amdgcn_mfma_f32_16x16x32_bf16(a1, bfr, acc31, 0, 0, 0);
    }

    float* Osh = (float*)As1;   // safe: Ysh reads all done before B4
    const float sj = gs[j], hj = gsh[j];
#pragma unroll
    for (int r = 0; r < 4; ++r) {
        Osh[j * 33 + rb + r]      = acc30[r] * sj + hj;
        Osh[j * 33 + 16 + rb + r] = acc31[r] * sj + hj;
    }
    __syncthreads();   // B5: Osh complete
    float* zb = z + (size_t)bb * CD * PLANE + pix0;
#pragma unroll
    for (int q = 0; q < 8; ++q) {
        const int idx = tid + (q << 8);
        const int jj = idx >> 5, t2 = idx & 31;
        zb[(size_t)jj * PLANE + t2] = Osh[jj * 33 + t2];
    }
}

// ---------------------------------------------------------------------------
extern "C" void kernel_launch(void* const* d_in, const int* in_sizes, int n_in,
                              void* d_out, int out_size, void* d_ws, size_t ws_size,
                              hipStream_t stream)
{
    (void)in_sizes; (void)n_in; (void)out_size; (void)ws_size;
    const float* x        = (const float*)d_in[0];
    const float* reduce_w = (const float*)d_in[1];
    const float* reduce_b = (const float*)d_in[2];
    const float* dw_w     = (const float*)d_in[3];
    const float* dw_b     = (const float*)d_in[4];
    const float* dw_g     = (const float*)d_in[5];
    const float* dw_beta  = (const float*)d_in[6];
    const float* dw_m     = (const float*)d_in[7];
    const float* dw_v     = (const float*)d_in[8];
    const float* f2_w     = (const float*)d_in[9];
    const float* f2_b     = (const float*)d_in[10];
    const float* coef     = (const float*)d_in[11];
    const float* sbase    = (const float*)d_in[12];
    const float* ssp      = (const float*)d_in[13];
    const float* kbias    = (const float*)d_in[14];
    const float* g_w      = (const float*)d_in[15];
    const float* g_b      = (const float*)d_in[16];
    const float* g_g      = (const float*)d_in[17];
    const float* g_beta   = (const float*)d_in[18];
    const float* g_m      = (const float*)d_in[19];
    const float* g_v      = (const float*)d_in[20];
    const float* dw2_w    = (const float*)d_in[21];
    const float* dw2_b    = (const float*)d_in[22];
    float* out = (float*)d_out;

    const size_t NEL = (size_t)BSZ * CD * PLANE;
    short* W1f = (short*)d_ws;
    short* W2f = W1f + 36864;
    short* WRf = W2f + 8192;
    short* WGf = WRf + 8192;
    float* cbuf = (float*)((char*)d_ws + 115200);
    float* inp = (float*)((char*)d_ws + 131072);
    float* xdb = inp + NEL;
    float* z   = xdb + NEL;

    k_prep<<<225, 256, 0, stream>>>(coef, ssp, sbase, f2_w, reduce_w, g_w,
                                    dw_g, dw_beta, dw_m, dw_v, dw_b,
                                    g_g, g_beta, g_m, g_v, g_b,
                                    W1f, W2f, WRf, WGf, cbuf);
    k_reduce_mfma<<<BSZ * 32, 256, 0, stream>>>(x, WRf, reduce_b, inp);
    k_dwconv<false><<<BSZ * 16 * 4, 256, 0, stream>>>(inp, dw_w, cbuf, cbuf + 64, nullptr, xdb);
    k_kan_fused<<<NPIX / 32, 256, 0, stream>>>(xdb, W1f, W2f, WGf, kbias, f2_b,
                                               cbuf + 128, cbuf + 192, z);
    k_dwconv<true><<<BSZ * 16 * 4, 256, 0, stream>>>(z, dw2_w, nullptr, dw2_b, inp, out);
}